// Round 1
// baseline (383.271 us; speedup 1.0000x reference)
//
#include <hip/hip_runtime.h>
#include <hip/hip_bf16.h>
#include <cstdint>

#define N_TOK 744
#define NP    768           // padded token count (mult of 64, covers 12x64 tiles)
#define DW    128           // d_model
#define NH    8

typedef __attribute__((ext_vector_type(4))) float f32x4;
typedef __attribute__((ext_vector_type(8))) __bf16 bf16x8;
typedef __attribute__((ext_vector_type(4))) __bf16 bf16x4;

// ---------------- Z init: Z = 1.0 (the appended zero-logit contributes exp(0)=1) ---
__global__ void k_zinit(float* Z, int n) {
    int i = blockIdx.x * 256 + threadIdx.x;
    if (i < n) Z[i] = 1.0f;
}

// ---------------- QV projection: v = x @ wqv_w^T + b, routed to q / vf_t / vb_t ----
// GEMM M=B*744, N=3072, K=128, bf16 MFMA 16x16x32.
// A frag: lane holds A[l&15][8*(l>>4)+j]; B frag: B[8*(l>>4)+j][l&15];
// D: D[(l>>4)*4+j][l&15]  (m89-verified C/D layout)
__global__ __launch_bounds__(256) void k_proj(
    const float* __restrict__ x, const float* __restrict__ wqv_w,
    const float* __restrict__ wqv_b,
    float* __restrict__ qbuf, __bf16* __restrict__ vf_t, __bf16* __restrict__ vb_t,
    int M)
{
    int tid = threadIdx.x;
    int l = tid & 63, wv = tid >> 6;
    int lr = l & 15, lg = l >> 4;
    int mbase = blockIdx.y * 64 + wv * 16;
    int c0 = blockIdx.x * 64;
    f32x4 acc[4] = {};
    for (int kk = 0; kk < 128; kk += 32) {
        int ka = kk + lg * 8;
        int ra = mbase + lr; if (ra >= M) ra = 0;   // clamp, store-guarded
        const float* ap = x + (size_t)ra * DW + ka;
        float a0[8];
        *(f32x4*)a0 = *(const f32x4*)ap; *(f32x4*)(a0 + 4) = *(const f32x4*)(ap + 4);
        bf16x8 af;
        for (int j = 0; j < 8; j++) af[j] = (__bf16)a0[j];
        for (int ct = 0; ct < 4; ct++) {
            int cb = c0 + ct * 16 + lr;
            const float* bp = wqv_w + (size_t)cb * DW + ka;
            float b0[8];
            *(f32x4*)b0 = *(const f32x4*)bp; *(f32x4*)(b0 + 4) = *(const f32x4*)(bp + 4);
            bf16x8 bfr;
            for (int j = 0; j < 8; j++) bfr[j] = (__bf16)b0[j];
            acc[ct] = __builtin_amdgcn_mfma_f32_16x16x32_bf16(af, bfr, acc[ct], 0, 0, 0);
        }
    }
    for (int ct = 0; ct < 4; ct++) {
        int c = c0 + ct * 16 + lr;
        int hd = c >> 7, wi = c & 127;
        float bias = wqv_b[c];
        for (int j = 0; j < 4; j++) {
            int r = mbase + lg * 4 + j;
            if (r >= M) continue;
            int b = r / N_TOK, s = r % N_TOK;
            float val = acc[ct][j] + bias;
            if (hd < 8) {
                qbuf[(((size_t)b * NH + hd) * NP + s) * DW + wi] = val;
            } else if (hd < 16) {
                vf_t[(((size_t)b * NH + (hd - 8)) * DW + wi) * NP + s] = (__bf16)val;
            } else {
                vb_t[(((size_t)b * NH + (hd - 16)) * DW + wi) * NP + s] = (__bf16)val;
            }
        }
    }
}

// ---------------- L1 scores + exp, dual-layout store + column-sum Z ----------------
// S[i][j] = -sum_w |q[b,i,h,w] - x[b,j,w]*wk[h,w]| * scale   (i = softmax axis)
// e2[i][j] = exp(S) natural; e1[j][i] = exp(S) transposed; Z[j] += colsum.
__global__ __launch_bounds__(256) void k_scores(
    const float* __restrict__ qbuf, const float* __restrict__ x,
    const float* __restrict__ wk,
    __bf16* __restrict__ e1, __bf16* __restrict__ e2, float* __restrict__ Z)
{
    __shared__ float qt[32][68];   // [w-chunk][s-tile], stride 68: 16B-aligned rows
    __shared__ float kt[32][68];
    int bh = blockIdx.z; int b = bh >> 3, h = bh & 7;
    int s0 = blockIdx.y * 64, d0 = blockIdx.x * 64;
    int tid = threadIdx.x;
    int si = tid >> 4, di = tid & 15;
    const float* qbase = qbuf + (size_t)bh * NP * DW;
    const float* xbase = x + (size_t)b * N_TOK * DW;
    const float* wkh = wk + h * DW;
    float acc[4][4] = {};
    for (int wc = 0; wc < 128; wc += 32) {
        int wi = tid & 31, r0 = tid >> 5;
        for (int p = 0; p < 8; p++) {
            int rr = r0 + p * 8;
            qt[wi][rr] = qbase[(size_t)(s0 + rr) * DW + wc + wi];   // padded buffer: safe
            int d = d0 + rr;
            float xv = (d < N_TOK) ? xbase[(size_t)d * DW + wc + wi] : 0.0f;
            kt[wi][rr] = xv * wkh[wc + wi];
        }
        __syncthreads();
        for (int w2 = 0; w2 < 32; w2++) {
            f32x4 q4 = *(const f32x4*)&qt[w2][si * 4];
            f32x4 k4 = *(const f32x4*)&kt[w2][di * 4];
            #pragma unroll
            for (int i = 0; i < 4; i++)
                #pragma unroll
                for (int j = 0; j < 4; j++)
                    acc[i][j] += fabsf(q4[i] - k4[j]);
        }
        __syncthreads();
    }
    const float scale = 0.08838834764831845f;
    float e[4][4]; float colsum[4] = {0, 0, 0, 0};
    for (int i = 0; i < 4; i++) {
        int s = s0 + si * 4 + i;
        for (int j = 0; j < 4; j++) {
            int d = d0 + di * 4 + j;
            float ev = (s < N_TOK && d < N_TOK) ? __expf(-acc[i][j] * scale) : 0.0f;
            e[i][j] = ev; colsum[j] += ev;
        }
    }
    size_t ebase = (size_t)bh * NP * NP;
    for (int i = 0; i < 4; i++) {
        int s = s0 + si * 4 + i;
        bf16x4 v; v[0] = (__bf16)e[i][0]; v[1] = (__bf16)e[i][1];
        v[2] = (__bf16)e[i][2]; v[3] = (__bf16)e[i][3];
        *(bf16x4*)&e2[ebase + (size_t)s * NP + d0 + di * 4] = v;
    }
    for (int j = 0; j < 4; j++) {
        int d = d0 + di * 4 + j;
        bf16x4 v; v[0] = (__bf16)e[0][j]; v[1] = (__bf16)e[1][j];
        v[2] = (__bf16)e[2][j]; v[3] = (__bf16)e[3][j];
        *(bf16x4*)&e1[ebase + (size_t)d * NP + s0 + si * 4] = v;
    }
    // Z column reduce (reuse qt as scratch [16][64])
    float* red = &qt[0][0];
    for (int j = 0; j < 4; j++) red[si * 64 + di * 4 + j] = colsum[j];
    __syncthreads();
    if (tid < 64) {
        float zz = 0;
        for (int r = 0; r < 16; r++) zz += red[r * 64 + tid];
        atomicAdd(&Z[(size_t)bh * NP + d0 + tid], zz);   // pads add 0: harmless
    }
}

// ---------------- fold 1/Z[token] into Vb (in place; rewritten by proj each call) --
__global__ void k_scalevb(__bf16* vb_t, const float* __restrict__ Z, long total8)
{
    long idx = (long)blockIdx.x * blockDim.x + threadIdx.x;
    if (idx >= total8) return;
    size_t base = (size_t)idx * 8;
    int s = (int)(base % NP);
    int bh = (int)((base / NP) / DW);
    bf16x8 v = *(bf16x8*)&vb_t[base];
    const float* Zp = Z + (size_t)bh * NP + s;
    bf16x8 o;
    #pragma unroll
    for (int i = 0; i < 8; i++) o[i] = (__bf16)((float)v[i] / Zp[i]);
    *(bf16x8*)&vb_t[base] = o;
}

// ---------------- attention apply: two MFMA GEMMs per (b,h), K = token dim ---------
// bf[j,w] = (1/Z[j]) * sum_i e1[j][i] * Vf_t[w][i]
// bb[i,w] =            sum_j e2[i][j] * Vb_t'[w][j]
__global__ __launch_bounds__(128) void k_apply(
    const __bf16* __restrict__ e1, const __bf16* __restrict__ e2,
    const __bf16* __restrict__ vf_t, const __bf16* __restrict__ vb_t,
    const float* __restrict__ Z, float* __restrict__ y0p)
{
    int bh = blockIdx.y;
    int tid = threadIdx.x;
    int l = tid & 63, wv = tid >> 6;
    int lr = l & 15, lg = l >> 4;
    int m0 = blockIdx.x * 32 + wv * 16;
    f32x4 accF[8] = {}; f32x4 accB[8] = {};
    size_t ebase = (size_t)bh * NP * NP;
    size_t vbase = (size_t)bh * DW * NP;
    const __bf16* e1r = e1 + ebase + (size_t)(m0 + lr) * NP;
    const __bf16* e2r = e2 + ebase + (size_t)(m0 + lr) * NP;
    for (int kk = 0; kk < NP; kk += 32) {
        int ko = kk + lg * 8;
        bf16x8 a1 = *(const bf16x8*)(e1r + ko);
        bf16x8 a2 = *(const bf16x8*)(e2r + ko);
        #pragma unroll
        for (int ct = 0; ct < 8; ct++) {
            bf16x8 bF = *(const bf16x8*)(vf_t + vbase + (size_t)(ct * 16 + lr) * NP + ko);
            accF[ct] = __builtin_amdgcn_mfma_f32_16x16x32_bf16(a1, bF, accF[ct], 0, 0, 0);
            bf16x8 bB = *(const bf16x8*)(vb_t + vbase + (size_t)(ct * 16 + lr) * NP + ko);
            accB[ct] = __builtin_amdgcn_mfma_f32_16x16x32_bf16(a2, bB, accB[ct], 0, 0, 0);
        }
    }
    float invZd[4];
    #pragma unroll
    for (int j = 0; j < 4; j++) invZd[j] = 1.0f / Z[(size_t)bh * NP + m0 + lg * 4 + j];
    float* yb = y0p + ((size_t)bh * NP + m0) * DW;
    #pragma unroll
    for (int ct = 0; ct < 8; ct++)
        #pragma unroll
        for (int j = 0; j < 4; j++)
            yb[(size_t)(lg * 4 + j) * DW + ct * 16 + lr] = invZd[j] * accF[ct][j] + accB[ct][j];
}

// ---------------- h-reduce + qgelu + fanin GEMM + residual -------------------------
__global__ __launch_bounds__(128) void k_fin(
    const float* __restrict__ y0p, const float* __restrict__ x,
    const float* __restrict__ fanin_w, const float* __restrict__ fanin_b,
    float* __restrict__ out)
{
    __shared__ float g[DW];
    int r = blockIdx.x;
    int b = r / N_TOK, s = r % N_TOK;
    int c = threadIdx.x;
    float acc = 0.0f;
    #pragma unroll
    for (int h = 0; h < NH; h++)
        acc += y0p[(((size_t)b * NH + h) * NP + s) * DW + c];
    float z = acc + 4.5f;
    float gv = z / (1.0f + __expf(-1.702f * z)) - 4.5f;
    g[c] = gv;
    __syncthreads();
    float o = fanin_b[c];
    const float* fw = fanin_w + (size_t)c * DW;
    #pragma unroll 8
    for (int k = 0; k < DW; k++) o += g[k] * fw[k];
    out[(size_t)r * DW + c] = x[(size_t)r * DW + c] + o;
}

extern "C" void kernel_launch(void* const* d_in, const int* in_sizes, int n_in,
                              void* d_out, int out_size, void* d_ws, size_t ws_size,
                              hipStream_t stream)
{
    const float* x       = (const float*)d_in[0];
    const float* wk      = (const float*)d_in[1];
    const float* wqv_w   = (const float*)d_in[2];
    const float* wqv_b   = (const float*)d_in[3];
    const float* fanin_w = (const float*)d_in[4];
    const float* fanin_b = (const float*)d_in[5];
    int B = in_sizes[0] / (N_TOK * DW);
    int M = B * N_TOK;

    char* ws = (char*)d_ws;
    size_t off = 0;
    float*  qbuf = (float*)(ws + off);  off += (size_t)B * NH * NP * DW * 4;
    __bf16* vf_t = (__bf16*)(ws + off); off += (size_t)B * NH * DW * NP * 2;
    __bf16* vb_t = (__bf16*)(ws + off); off += (size_t)B * NH * DW * NP * 2;
    __bf16* e1   = (__bf16*)(ws + off); off += (size_t)B * NH * NP * NP * 2;
    __bf16* e2   = (__bf16*)(ws + off); off += (size_t)B * NH * NP * NP * 2;
    float*  Z    = (float*)(ws + off);  off += (size_t)B * NH * NP * 4;
    float*  y0p  = (float*)(ws + off);  off += (size_t)B * NH * NP * DW * 4;
    if (off > ws_size) return;   // fail loudly via validation rather than fault

    int zn = B * NH * NP;
    k_zinit<<<(zn + 255) / 256, 256, 0, stream>>>(Z, zn);

    dim3 gp(3072 / 64, (M + 63) / 64);
    k_proj<<<gp, 256, 0, stream>>>(x, wqv_w, wqv_b, qbuf, vf_t, vb_t, M);

    dim3 gs(NP / 64, NP / 64, B * NH);
    k_scores<<<gs, 256, 0, stream>>>(qbuf, x, wk, e1, e2, Z);

    long total8 = (long)B * NH * DW * NP / 8;
    k_scalevb<<<(int)((total8 + 255) / 256), 256, 0, stream>>>(vb_t, Z, total8);

    dim3 ga(NP / 32, B * NH);
    k_apply<<<ga, 128, 0, stream>>>(e1, e2, vf_t, vb_t, Z, y0p);

    k_fin<<<M, 128, 0, stream>>>(y0p, x, fanin_w, fanin_b, (float*)d_out);
}

// Round 3
// 381.658 us; speedup vs baseline: 1.0042x; 1.0042x over previous
//
#include <hip/hip_runtime.h>
#include <hip/hip_bf16.h>
#include <cstdint>

#define N_TOK 744
#define NP    768           // padded token count
#define DW    128           // d_model
#define NH    8

typedef __attribute__((ext_vector_type(4))) float f32x4;
typedef __attribute__((ext_vector_type(4))) unsigned int u32x4;
typedef __attribute__((ext_vector_type(8))) __bf16 bf16x8;
typedef __attribute__((ext_vector_type(4))) __bf16 bf16x4;

__device__ __forceinline__ unsigned int sadu32(unsigned int a, unsigned int b, unsigned int c) {
    unsigned int d;
    asm("v_sad_u32 %0, %1, %2, %3" : "=v"(d) : "v"(a), "v"(b), "v"(c));
    return d;
}

// ---------------- Z init: Z = 1.0 (appended zero-logit contributes exp(0)=1) -------
__global__ void k_zinit(float* Z, int n) {
    int i = blockIdx.x * 256 + threadIdx.x;
    if (i < n) Z[i] = 1.0f;
}

// ---------------- QV projection: v = x @ wqv_w^T + b, routed to q / vf_t / vb_t ----
__global__ __launch_bounds__(256) void k_proj(
    const float* __restrict__ x, const float* __restrict__ wqv_w,
    const float* __restrict__ wqv_b,
    float* __restrict__ qbuf, __bf16* __restrict__ vf_t, __bf16* __restrict__ vb_t,
    int M)
{
    int tid = threadIdx.x;
    int l = tid & 63, wv = tid >> 6;
    int lr = l & 15, lg = l >> 4;
    int mbase = blockIdx.y * 64 + wv * 16;
    int c0 = blockIdx.x * 64;
    f32x4 acc[4] = {};
    for (int kk = 0; kk < 128; kk += 32) {
        int ka = kk + lg * 8;
        int ra = mbase + lr; if (ra >= M) ra = 0;   // clamp, store-guarded
        const float* ap = x + (size_t)ra * DW + ka;
        float a0[8];
        *(f32x4*)a0 = *(const f32x4*)ap; *(f32x4*)(a0 + 4) = *(const f32x4*)(ap + 4);
        bf16x8 af;
        for (int j = 0; j < 8; j++) af[j] = (__bf16)a0[j];
        for (int ct = 0; ct < 4; ct++) {
            int cb = c0 + ct * 16 + lr;
            const float* bp = wqv_w + (size_t)cb * DW + ka;
            float b0[8];
            *(f32x4*)b0 = *(const f32x4*)bp; *(f32x4*)(b0 + 4) = *(const f32x4*)(bp + 4);
            bf16x8 bfr;
            for (int j = 0; j < 8; j++) bfr[j] = (__bf16)b0[j];
            acc[ct] = __builtin_amdgcn_mfma_f32_16x16x32_bf16(af, bfr, acc[ct], 0, 0, 0);
        }
    }
    for (int ct = 0; ct < 4; ct++) {
        int c = c0 + ct * 16 + lr;
        int hd = c >> 7, wi = c & 127;
        float bias = wqv_b[c];
        for (int j = 0; j < 4; j++) {
            int r = mbase + lg * 4 + j;
            if (r >= M) continue;
            int b = r / N_TOK, s = r % N_TOK;
            float val = acc[ct][j] + bias;
            if (hd < 8) {
                qbuf[(((size_t)b * NH + hd) * NP + s) * DW + wi] = val;
            } else if (hd < 16) {
                vf_t[(((size_t)b * NH + (hd - 8)) * DW + wi) * NP + s] = (__bf16)val;
            } else {
                vb_t[(((size_t)b * NH + (hd - 16)) * DW + wi) * NP + s] = (__bf16)val;
            }
        }
    }
}

// ---------------- L1 scores via v_sad_u32 fixed-point, dual-layout e + Z -----------
// fixed point: u = (q + 4.0) * 2^22;  sum_w |uq-uk| = 2^22 * sum_w |q-k|
__global__ __launch_bounds__(256) void k_scores(
    const float* __restrict__ qbuf, const float* __restrict__ x,
    const float* __restrict__ wk,
    __bf16* __restrict__ e1, __bf16* __restrict__ e2, float* __restrict__ Z)
{
    __shared__ unsigned int qt[32][132];   // [w-chunk][s-row], pad 132 (16B-aligned rows)
    __shared__ unsigned int kt[32][132];
    int bh = blockIdx.z; int b = bh >> 3, h = bh & 7;
    int s0 = blockIdx.y * 128, d0 = blockIdx.x * 128;
    int tid = threadIdx.x;
    int ty = tid >> 4, tx = tid & 15;      // 16x16 threads, each 8x8 outputs
    const float* qbase = qbuf + (size_t)bh * NP * DW;
    const float* xbase = x + (size_t)b * N_TOK * DW;
    const float* wkh = wk + h * DW;
    unsigned int acc[8][8] = {};
    int wlane = tid & 31, rbase = tid >> 5;
    for (int wc = 0; wc < 128; wc += 32) {
        float wkv = wkh[wc + wlane];
        #pragma unroll
        for (int p = 0; p < 32; p++) {
            int rr = p * 8 + rbase;                     // 0..255, uniform branch per p
            if (rr < 128) {
                float v = qbase[(size_t)(s0 + rr) * DW + wc + wlane];
                qt[wlane][rr] = (unsigned int)__builtin_fmaf(v, 4194304.0f, 16777216.0f);
            } else {
                int d = d0 + rr - 128;
                float xv = (d < N_TOK) ? xbase[(size_t)d * DW + wc + wlane] : 0.0f;
                kt[wlane][rr - 128] = (unsigned int)__builtin_fmaf(xv * wkv, 4194304.0f, 16777216.0f);
            }
        }
        __syncthreads();
        #pragma unroll 2
        for (int w2 = 0; w2 < 32; w2++) {
            unsigned int qv[8], kv[8];
            *(u32x4*)&qv[0] = *(const u32x4*)&qt[w2][ty * 8];
            *(u32x4*)&qv[4] = *(const u32x4*)&qt[w2][ty * 8 + 4];
            *(u32x4*)&kv[0] = *(const u32x4*)&kt[w2][tx * 8];
            *(u32x4*)&kv[4] = *(const u32x4*)&kt[w2][tx * 8 + 4];
            #pragma unroll
            for (int i = 0; i < 8; i++)
                #pragma unroll
                for (int j = 0; j < 8; j++)
                    acc[i][j] = sadu32(qv[i], kv[j], acc[i][j]);
        }
        __syncthreads();
    }
    const float SS = 0.08838834764831845f / 4194304.0f;
    float e[8][8]; float colsum[8] = {};
    int sb = s0 + ty * 8, db = d0 + tx * 8;
    #pragma unroll
    for (int i = 0; i < 8; i++)
        #pragma unroll
        for (int j = 0; j < 8; j++) {
            float ev = ((sb + i) < N_TOK && (db + j) < N_TOK)
                       ? __expf(-(float)acc[i][j] * SS) : 0.0f;
            e[i][j] = ev; colsum[j] += ev;
        }
    size_t ebase = (size_t)bh * NP * NP;
    #pragma unroll
    for (int i = 0; i < 8; i++) {
        bf16x8 v;
        #pragma unroll
        for (int j = 0; j < 8; j++) v[j] = (__bf16)e[i][j];
        *(bf16x8*)&e2[ebase + (size_t)(sb + i) * NP + db] = v;
    }
    #pragma unroll
    for (int j = 0; j < 8; j++) {
        bf16x8 v;
        #pragma unroll
        for (int i = 0; i < 8; i++) v[i] = (__bf16)e[i][j];
        *(bf16x8*)&e1[ebase + (size_t)(db + j) * NP + sb] = v;
    }
    // Z column reduce over the 16 ty groups
    float* red = (float*)&qt[0][0];     // 16x128 f32 = 8 KB
    #pragma unroll
    for (int j = 0; j < 8; j++) red[ty * 128 + tx * 8 + j] = colsum[j];
    __syncthreads();
    if (tid < 128) {
        float z = 0;
        #pragma unroll
        for (int r = 0; r < 16; r++) z += red[r * 128 + tid];
        atomicAdd(&Z[(size_t)bh * NP + d0 + tid], z);
    }
}

// ---------------- fold 1/Z[token] into Vb (in place) ------------------------------
__global__ void k_scalevb(__bf16* vb_t, const float* __restrict__ Z, long total8)
{
    long idx = (long)blockIdx.x * blockDim.x + threadIdx.x;
    if (idx >= total8) return;
    size_t base = (size_t)idx * 8;
    int s = (int)(base % NP);
    int bh = (int)((base / NP) / DW);
    bf16x8 v = *(bf16x8*)&vb_t[base];
    const float* Zp = Z + (size_t)bh * NP + s;
    bf16x8 o;
    #pragma unroll
    for (int i = 0; i < 8; i++) o[i] = (__bf16)((float)v[i] / Zp[i]);
    *(bf16x8*)&vb_t[base] = o;
}

// ---------------- attention apply: GEMMs split across waves (F: wv<2, B: wv>=2) ----
__global__ __launch_bounds__(256) void k_apply(
    const __bf16* __restrict__ e1, const __bf16* __restrict__ e2,
    const __bf16* __restrict__ vf_t, const __bf16* __restrict__ vb_t,
    const float* __restrict__ Z, float* __restrict__ y0f, float* __restrict__ y0b)
{
    int bh = blockIdx.y;
    int tid = threadIdx.x;
    int l = tid & 63, wv = tid >> 6;
    int lr = l & 15, lg = l >> 4;
    int m0 = blockIdx.x * 32 + (wv & 1) * 16;
    bool doF = (wv < 2);
    const __bf16* E = doF ? e1 : e2;
    const __bf16* V = doF ? vf_t : vb_t;
    f32x4 acc[8] = {};
    const __bf16* er = E + (size_t)bh * NP * NP + (size_t)(m0 + lr) * NP;
    const __bf16* vp = V + (size_t)bh * DW * NP;
    #pragma unroll 2
    for (int kk = 0; kk < NP; kk += 32) {
        int ko = kk + lg * 8;
        bf16x8 a = *(const bf16x8*)(er + ko);
        #pragma unroll
        for (int ct = 0; ct < 8; ct++) {
            bf16x8 bfr = *(const bf16x8*)(vp + (size_t)(ct * 16 + lr) * NP + ko);
            acc[ct] = __builtin_amdgcn_mfma_f32_16x16x32_bf16(a, bfr, acc[ct], 0, 0, 0);
        }
    }
    float sc[4];
    #pragma unroll
    for (int j = 0; j < 4; j++)
        sc[j] = doF ? (1.0f / Z[(size_t)bh * NP + m0 + lg * 4 + j]) : 1.0f;
    float* yb = (doF ? y0f : y0b) + ((size_t)bh * NP + m0) * DW;
    #pragma unroll
    for (int ct = 0; ct < 8; ct++)
        #pragma unroll
        for (int j = 0; j < 4; j++)
            yb[(size_t)(lg * 4 + j) * DW + ct * 16 + lr] = sc[j] * acc[ct][j];
}

// ---------------- h-reduce + qgelu -> g (bf16) -------------------------------------
__global__ __launch_bounds__(256) void k_fin1(
    const float* __restrict__ y0f, const float* __restrict__ y0b,
    __bf16* __restrict__ g, int M)
{
    int idx = blockIdx.x * 256 + threadIdx.x;  // one per 4 cols
    int r = idx >> 5;
    int c = (idx & 31) * 4;
    if (r >= M) return;
    int b = r / N_TOK, s = r % N_TOK;
    f32x4 sum = {};
    size_t base = ((size_t)b * NH * NP + s) * DW + c;
    #pragma unroll
    for (int h = 0; h < NH; h++) {
        sum += *(const f32x4*)&y0f[base + (size_t)h * NP * DW];
        sum += *(const f32x4*)&y0b[base + (size_t)h * NP * DW];
    }
    bf16x4 o;
    #pragma unroll
    for (int i = 0; i < 4; i++) {
        float z = sum[i] + 4.5f;
        float gv = z / (1.0f + __expf(-1.702f * z)) - 4.5f;
        o[i] = (__bf16)gv;
    }
    *(bf16x4*)&g[(size_t)r * DW + c] = o;
}

// ---------------- fanin MFMA GEMM + residual ---------------------------------------
__global__ __launch_bounds__(256) void k_fin2(
    const __bf16* __restrict__ g, const float* __restrict__ x,
    const float* __restrict__ fanin_w, const float* __restrict__ fanin_b,
    float* __restrict__ out, int M)
{
    int tid = threadIdx.x;
    int l = tid & 63, wv = tid >> 6;
    int lr = l & 15, lg = l >> 4;
    int m0 = blockIdx.x * 64 + wv * 16;
    f32x4 acc[8] = {};
    int ar = m0 + lr; if (ar >= M) ar = M - 1;
    const __bf16* gp = g + (size_t)ar * DW;
    for (int kk = 0; kk < 128; kk += 32) {
        int ko = kk + lg * 8;
        bf16x8 a = *(const bf16x8*)(gp + ko);
        #pragma unroll
        for (int ct = 0; ct < 8; ct++) {
            const float* wp = fanin_w + (size_t)(ct * 16 + lr) * DW + ko;
            float w0[8];
            *(f32x4*)w0 = *(const f32x4*)wp; *(f32x4*)(w0 + 4) = *(const f32x4*)(wp + 4);
            bf16x8 bfr;
            #pragma unroll
            for (int j2 = 0; j2 < 8; j2++) bfr[j2] = (__bf16)w0[j2];
            acc[ct] = __builtin_amdgcn_mfma_f32_16x16x32_bf16(a, bfr, acc[ct], 0, 0, 0);
        }
    }
    #pragma unroll
    for (int ct = 0; ct < 8; ct++) {
        int c = ct * 16 + lr;
        float fb = fanin_b[c];
        #pragma unroll
        for (int j = 0; j < 4; j++) {
            int r = m0 + lg * 4 + j;
            if (r < M) out[(size_t)r * DW + c] = x[(size_t)r * DW + c] + acc[ct][j] + fb;
        }
    }
}

extern "C" void kernel_launch(void* const* d_in, const int* in_sizes, int n_in,
                              void* d_out, int out_size, void* d_ws, size_t ws_size,
                              hipStream_t stream)
{
    const float* x       = (const float*)d_in[0];
    const float* wk      = (const float*)d_in[1];
    const float* wqv_w   = (const float*)d_in[2];
    const float* wqv_b   = (const float*)d_in[3];
    const float* fanin_w = (const float*)d_in[4];
    const float* fanin_b = (const float*)d_in[5];
    int B = in_sizes[0] / (N_TOK * DW);
    int M = B * N_TOK;

    char* ws = (char*)d_ws;
    size_t off = 0;
    float*  qbuf = (float*)(ws + off);  off += (size_t)B * NH * NP * DW * 4;  // also y0f
    __bf16* vf_t = (__bf16*)(ws + off); off += (size_t)B * NH * DW * NP * 2;  // also g
    __bf16* vb_t = (__bf16*)(ws + off); off += (size_t)B * NH * DW * NP * 2;
    __bf16* e1   = (__bf16*)(ws + off); off += (size_t)B * NH * NP * NP * 2;
    __bf16* e2   = (__bf16*)(ws + off); off += (size_t)B * NH * NP * NP * 2;
    float*  Z    = (float*)(ws + off);  off += (size_t)B * NH * NP * 4;
    float*  y0b  = (float*)(ws + off);  off += (size_t)B * NH * NP * DW * 4;
    if (off > ws_size) return;
    float*  y0f = qbuf;          // qbuf dead after k_scores
    __bf16* g   = vf_t;          // vf_t dead after k_apply

    int zn = B * NH * NP;
    k_zinit<<<(zn + 255) / 256, 256, 0, stream>>>(Z, zn);

    dim3 gp(3072 / 64, (M + 63) / 64);
    k_proj<<<gp, 256, 0, stream>>>(x, wqv_w, wqv_b, qbuf, vf_t, vb_t, M);

    dim3 gs(NP / 128, NP / 128, B * NH);
    k_scores<<<gs, 256, 0, stream>>>(qbuf, x, wk, e1, e2, Z);

    long total8 = (long)B * NH * DW * NP / 8;
    k_scalevb<<<(int)((total8 + 255) / 256), 256, 0, stream>>>(vb_t, Z, total8);

    dim3 ga(NP / 32, B * NH);
    k_apply<<<ga, 256, 0, stream>>>(e1, e2, vf_t, vb_t, Z, y0f, y0b);

    int f1blocks = (M * (DW / 4) + 255) / 256;
    k_fin1<<<f1blocks, 256, 0, stream>>>(y0f, y0b, g, M);

    k_fin2<<<(M + 63) / 64, 256, 0, stream>>>(g, x, fanin_w, fanin_b, (float*)d_out, M);
}

// Round 4
// 299.211 us; speedup vs baseline: 1.2809x; 1.2755x over previous
//
#include <hip/hip_runtime.h>
#include <hip/hip_bf16.h>
#include <cstdint>

#define N_TOK 744
#define NP    768           // padded token count
#define DW    128           // d_model
#define NH    8

typedef __attribute__((ext_vector_type(4))) float f32x4;
typedef __attribute__((ext_vector_type(4))) unsigned int u32x4;
typedef __attribute__((ext_vector_type(8))) __bf16 bf16x8;
typedef __attribute__((ext_vector_type(4))) __bf16 bf16x4;

__device__ __forceinline__ unsigned int sadu16(unsigned int a, unsigned int b, unsigned int c) {
    unsigned int d;
    asm("v_sad_u16 %0, %1, %2, %3" : "=v"(d) : "v"(a), "v"(b), "v"(c));
    return d;
}

// ---------------- Z init: Z = 1.0 (appended zero-logit contributes exp(0)=1) -------
__global__ void k_zinit(float* Z, int n) {
    int i = blockIdx.x * 256 + threadIdx.x;
    if (i < n) Z[i] = 1.0f;
}

// ---------------- QV projection: v = x @ wqv_w^T + b, routed to q / vf_t / vb_t ----
__global__ __launch_bounds__(256) void k_proj(
    const float* __restrict__ x, const float* __restrict__ wqv_w,
    const float* __restrict__ wqv_b,
    float* __restrict__ qbuf, __bf16* __restrict__ vf_t, __bf16* __restrict__ vb_t,
    int M)
{
    int tid = threadIdx.x;
    int l = tid & 63, wv = tid >> 6;
    int lr = l & 15, lg = l >> 4;
    int mbase = blockIdx.y * 64 + wv * 16;
    int c0 = blockIdx.x * 64;
    f32x4 acc[4] = {};
    for (int kk = 0; kk < 128; kk += 32) {
        int ka = kk + lg * 8;
        int ra = mbase + lr; if (ra >= M) ra = 0;   // clamp, store-guarded
        const float* ap = x + (size_t)ra * DW + ka;
        float a0[8];
        *(f32x4*)a0 = *(const f32x4*)ap; *(f32x4*)(a0 + 4) = *(const f32x4*)(ap + 4);
        bf16x8 af;
        for (int j = 0; j < 8; j++) af[j] = (__bf16)a0[j];
        for (int ct = 0; ct < 4; ct++) {
            int cb = c0 + ct * 16 + lr;
            const float* bp = wqv_w + (size_t)cb * DW + ka;
            float b0[8];
            *(f32x4*)b0 = *(const f32x4*)bp; *(f32x4*)(b0 + 4) = *(const f32x4*)(bp + 4);
            bf16x8 bfr;
            for (int j = 0; j < 8; j++) bfr[j] = (__bf16)b0[j];
            acc[ct] = __builtin_amdgcn_mfma_f32_16x16x32_bf16(af, bfr, acc[ct], 0, 0, 0);
        }
    }
    for (int ct = 0; ct < 4; ct++) {
        int c = c0 + ct * 16 + lr;
        int hd = c >> 7, wi = c & 127;
        float bias = wqv_b[c];
        for (int j = 0; j < 4; j++) {
            int r = mbase + lg * 4 + j;
            if (r >= M) continue;
            int b = r / N_TOK, s = r % N_TOK;
            float val = acc[ct][j] + bias;
            if (hd < 8) {
                qbuf[(((size_t)b * NH + hd) * NP + s) * DW + wi] = val;
            } else if (hd < 16) {
                vf_t[(((size_t)b * NH + (hd - 8)) * DW + wi) * NP + s] = (__bf16)val;
            } else {
                vb_t[(((size_t)b * NH + (hd - 16)) * DW + wi) * NP + s] = (__bf16)val;
            }
        }
    }
}

// ---------------- L1 scores via packed v_sad_u16 fixed point -----------------------
// u = (v + 2.0) * 2^14  (RN via +0.5 then trunc); two w's per u32.
// sum_w |uq-uk| = 2^14 * sum_w |q-k|
__global__ __launch_bounds__(256) void k_scores(
    const float* __restrict__ qbuf, const float* __restrict__ x,
    const float* __restrict__ wk,
    __bf16* __restrict__ e1, __bf16* __restrict__ e2, float* __restrict__ Z)
{
    __shared__ unsigned int qt[16][132];   // [w-pair][row], 528B rows (16B aligned)
    __shared__ unsigned int kt[16][132];
    int bh = blockIdx.z; int b = bh >> 3, h = bh & 7;
    int s0 = blockIdx.y * 128, d0 = blockIdx.x * 128;
    int tid = threadIdx.x;
    int ty = tid >> 4, tx = tid & 15;      // 16x16 threads, each 8x8 outputs
    const float* qbase = qbuf + (size_t)bh * NP * DW;
    const float* xbase = x + (size_t)b * N_TOK * DW;
    const float* wkh = wk + h * DW;
    unsigned int acc[8][8] = {};
    int lp = tid & 15;          // pair index 0..15 within chunk
    int lr0 = tid >> 4;         // row base 0..15
    for (int wc = 0; wc < 128; wc += 32) {
        float wk0 = wkh[wc + 2 * lp], wk1 = wkh[wc + 2 * lp + 1];
        #pragma unroll
        for (int pass = 0; pass < 8; pass++) {
            int r = pass * 16 + lr0;
            const float* qp = qbase + (size_t)(s0 + r) * DW + wc + 2 * lp;
            float q0 = qp[0], q1 = qp[1];
            unsigned int uq0 = (unsigned int)__builtin_fmaf(q0, 16384.0f, 32768.5f);
            unsigned int uq1 = (unsigned int)__builtin_fmaf(q1, 16384.0f, 32768.5f);
            qt[lp][r] = uq0 | (uq1 << 16);
            int d = d0 + r;
            float x0 = 0.0f, x1 = 0.0f;
            if (d < N_TOK) {
                const float* xp = xbase + (size_t)d * DW + wc + 2 * lp;
                x0 = xp[0]; x1 = xp[1];
            }
            unsigned int uk0 = (unsigned int)__builtin_fmaf(x0 * wk0, 16384.0f, 32768.5f);
            unsigned int uk1 = (unsigned int)__builtin_fmaf(x1 * wk1, 16384.0f, 32768.5f);
            kt[lp][r] = uk0 | (uk1 << 16);
        }
        __syncthreads();
        #pragma unroll
        for (int wp = 0; wp < 16; wp++) {
            unsigned int qv[8], kv[8];
            *(u32x4*)&qv[0] = *(const u32x4*)&qt[wp][ty * 8];
            *(u32x4*)&qv[4] = *(const u32x4*)&qt[wp][ty * 8 + 4];
            *(u32x4*)&kv[0] = *(const u32x4*)&kt[wp][tx * 8];
            *(u32x4*)&kv[4] = *(const u32x4*)&kt[wp][tx * 8 + 4];
            #pragma unroll
            for (int i = 0; i < 8; i++)
                #pragma unroll
                for (int j = 0; j < 8; j++)
                    acc[i][j] = sadu16(qv[i], kv[j], acc[i][j]);
        }
        __syncthreads();
    }
    const float SS = 0.08838834764831845f / 16384.0f;
    float e[8][8]; float colsum[8] = {};
    int sb = s0 + ty * 8, db = d0 + tx * 8;
    #pragma unroll
    for (int i = 0; i < 8; i++)
        #pragma unroll
        for (int j = 0; j < 8; j++) {
            float ev = ((sb + i) < N_TOK && (db + j) < N_TOK)
                       ? __expf(-(float)acc[i][j] * SS) : 0.0f;
            e[i][j] = ev; colsum[j] += ev;
        }
    size_t ebase = (size_t)bh * NP * NP;
    #pragma unroll
    for (int i = 0; i < 8; i++) {
        bf16x8 v;
        #pragma unroll
        for (int j = 0; j < 8; j++) v[j] = (__bf16)e[i][j];
        *(bf16x8*)&e2[ebase + (size_t)(sb + i) * NP + db] = v;
    }
    #pragma unroll
    for (int j = 0; j < 8; j++) {
        bf16x8 v;
        #pragma unroll
        for (int i = 0; i < 8; i++) v[i] = (__bf16)e[i][j];
        *(bf16x8*)&e1[ebase + (size_t)(db + j) * NP + sb] = v;
    }
    // Z column reduce over the 16 ty groups (reuse qt as 16x128 f32 scratch)
    float* red = (float*)&qt[0][0];
    #pragma unroll
    for (int j = 0; j < 8; j++) red[ty * 128 + tx * 8 + j] = colsum[j];
    __syncthreads();
    if (tid < 128) {
        float z = 0;
        #pragma unroll
        for (int r = 0; r < 16; r++) z += red[r * 128 + tid];
        atomicAdd(&Z[(size_t)bh * NP + d0 + tid], z);
    }
}

// ---------------- fold 1/Z[token] into Vb (in place) ------------------------------
__global__ void k_scalevb(__bf16* vb_t, const float* __restrict__ Z, long total8)
{
    long idx = (long)blockIdx.x * blockDim.x + threadIdx.x;
    if (idx >= total8) return;
    size_t base = (size_t)idx * 8;
    int s = (int)(base % NP);
    int bh = (int)((base / NP) / DW);
    bf16x8 v = *(bf16x8*)&vb_t[base];
    const float* Zp = Z + (size_t)bh * NP + s;
    bf16x8 o;
    #pragma unroll
    for (int i = 0; i < 8; i++) o[i] = (__bf16)((float)v[i] / Zp[i]);
    *(bf16x8*)&vb_t[base] = o;
}

// ---------------- attention apply: GEMMs split across waves (F: wv<2, B: wv>=2) ----
__global__ __launch_bounds__(256) void k_apply(
    const __bf16* __restrict__ e1, const __bf16* __restrict__ e2,
    const __bf16* __restrict__ vf_t, const __bf16* __restrict__ vb_t,
    const float* __restrict__ Z, float* __restrict__ y0f, float* __restrict__ y0b)
{
    int bh = blockIdx.y;
    int tid = threadIdx.x;
    int l = tid & 63, wv = tid >> 6;
    int lr = l & 15, lg = l >> 4;
    int m0 = blockIdx.x * 32 + (wv & 1) * 16;
    bool doF = (wv < 2);
    const __bf16* E = doF ? e1 : e2;
    const __bf16* V = doF ? vf_t : vb_t;
    f32x4 acc[8] = {};
    const __bf16* er = E + (size_t)bh * NP * NP + (size_t)(m0 + lr) * NP;
    const __bf16* vp = V + (size_t)bh * DW * NP;
    #pragma unroll 2
    for (int kk = 0; kk < NP; kk += 32) {
        int ko = kk + lg * 8;
        bf16x8 a = *(const bf16x8*)(er + ko);
        #pragma unroll
        for (int ct = 0; ct < 8; ct++) {
            bf16x8 bfr = *(const bf16x8*)(vp + (size_t)(ct * 16 + lr) * NP + ko);
            acc[ct] = __builtin_amdgcn_mfma_f32_16x16x32_bf16(a, bfr, acc[ct], 0, 0, 0);
        }
    }
    float sc[4];
    #pragma unroll
    for (int j = 0; j < 4; j++)
        sc[j] = doF ? (1.0f / Z[(size_t)bh * NP + m0 + lg * 4 + j]) : 1.0f;
    float* yb = (doF ? y0f : y0b) + ((size_t)bh * NP + m0) * DW;
    #pragma unroll
    for (int ct = 0; ct < 8; ct++)
        #pragma unroll
        for (int j = 0; j < 4; j++)
            yb[(size_t)(lg * 4 + j) * DW + ct * 16 + lr] = sc[j] * acc[ct][j];
}

// ---------------- h-reduce + qgelu -> g (bf16) -------------------------------------
__global__ __launch_bounds__(256) void k_fin1(
    const float* __restrict__ y0f, const float* __restrict__ y0b,
    __bf16* __restrict__ g, int M)
{
    int idx = blockIdx.x * 256 + threadIdx.x;  // one per 4 cols
    int r = idx >> 5;
    int c = (idx & 31) * 4;
    if (r >= M) return;
    int b = r / N_TOK, s = r % N_TOK;
    f32x4 sum = {};
    size_t base = ((size_t)b * NH * NP + s) * DW + c;
    #pragma unroll
    for (int h = 0; h < NH; h++) {
        sum += *(const f32x4*)&y0f[base + (size_t)h * NP * DW];
        sum += *(const f32x4*)&y0b[base + (size_t)h * NP * DW];
    }
    bf16x4 o;
    #pragma unroll
    for (int i = 0; i < 4; i++) {
        float z = sum[i] + 4.5f;
        float gv = z / (1.0f + __expf(-1.702f * z)) - 4.5f;
        o[i] = (__bf16)gv;
    }
    *(bf16x4*)&g[(size_t)r * DW + c] = o;
}

// ---------------- fanin MFMA GEMM + residual ---------------------------------------
__global__ __launch_bounds__(256) void k_fin2(
    const __bf16* __restrict__ g, const float* __restrict__ x,
    const float* __restrict__ fanin_w, const float* __restrict__ fanin_b,
    float* __restrict__ out, int M)
{
    int tid = threadIdx.x;
    int l = tid & 63, wv = tid >> 6;
    int lr = l & 15, lg = l >> 4;
    int m0 = blockIdx.x * 64 + wv * 16;
    f32x4 acc[8] = {};
    int ar = m0 + lr; if (ar >= M) ar = M - 1;
    const __bf16* gp = g + (size_t)ar * DW;
    for (int kk = 0; kk < 128; kk += 32) {
        int ko = kk + lg * 8;
        bf16x8 a = *(const bf16x8*)(gp + ko);
        #pragma unroll
        for (int ct = 0; ct < 8; ct++) {
            const float* wp = fanin_w + (size_t)(ct * 16 + lr) * DW + ko;
            float w0[8];
            *(f32x4*)w0 = *(const f32x4*)wp; *(f32x4*)(w0 + 4) = *(const f32x4*)(wp + 4);
            bf16x8 bfr;
            #pragma unroll
            for (int j2 = 0; j2 < 8; j2++) bfr[j2] = (__bf16)w0[j2];
            acc[ct] = __builtin_amdgcn_mfma_f32_16x16x32_bf16(a, bfr, acc[ct], 0, 0, 0);
        }
    }
    #pragma unroll
    for (int ct = 0; ct < 8; ct++) {
        int c = ct * 16 + lr;
        float fb = fanin_b[c];
        #pragma unroll
        for (int j = 0; j < 4; j++) {
            int r = m0 + lg * 4 + j;
            if (r < M) out[(size_t)r * DW + c] = x[(size_t)r * DW + c] + acc[ct][j] + fb;
        }
    }
}

extern "C" void kernel_launch(void* const* d_in, const int* in_sizes, int n_in,
                              void* d_out, int out_size, void* d_ws, size_t ws_size,
                              hipStream_t stream)
{
    const float* x       = (const float*)d_in[0];
    const float* wk      = (const float*)d_in[1];
    const float* wqv_w   = (const float*)d_in[2];
    const float* wqv_b   = (const float*)d_in[3];
    const float* fanin_w = (const float*)d_in[4];
    const float* fanin_b = (const float*)d_in[5];
    int B = in_sizes[0] / (N_TOK * DW);
    int M = B * N_TOK;

    char* ws = (char*)d_ws;
    size_t off = 0;
    float*  qbuf = (float*)(ws + off);  off += (size_t)B * NH * NP * DW * 4;  // also y0f
    __bf16* vf_t = (__bf16*)(ws + off); off += (size_t)B * NH * DW * NP * 2;  // also g
    __bf16* vb_t = (__bf16*)(ws + off); off += (size_t)B * NH * DW * NP * 2;
    __bf16* e1   = (__bf16*)(ws + off); off += (size_t)B * NH * NP * NP * 2;
    __bf16* e2   = (__bf16*)(ws + off); off += (size_t)B * NH * NP * NP * 2;
    float*  Z    = (float*)(ws + off);  off += (size_t)B * NH * NP * 4;
    float*  y0b  = (float*)(ws + off);  off += (size_t)B * NH * NP * DW * 4;
    if (off > ws_size) return;
    float*  y0f = qbuf;          // qbuf dead after k_scores
    __bf16* g   = vf_t;          // vf_t dead after k_apply

    int zn = B * NH * NP;
    k_zinit<<<(zn + 255) / 256, 256, 0, stream>>>(Z, zn);

    dim3 gp(3072 / 64, (M + 63) / 64);
    k_proj<<<gp, 256, 0, stream>>>(x, wqv_w, wqv_b, qbuf, vf_t, vb_t, M);

    dim3 gs(NP / 128, NP / 128, B * NH);
    k_scores<<<gs, 256, 0, stream>>>(qbuf, x, wk, e1, e2, Z);

    long total8 = (long)B * NH * DW * NP / 8;
    k_scalevb<<<(int)((total8 + 255) / 256), 256, 0, stream>>>(vb_t, Z, total8);

    dim3 ga(NP / 32, B * NH);
    k_apply<<<ga, 256, 0, stream>>>(e1, e2, vf_t, vb_t, Z, y0f, y0b);

    int f1blocks = (M * (DW / 4) + 255) / 256;
    k_fin1<<<f1blocks, 256, 0, stream>>>(y0f, y0b, g, M);

    k_fin2<<<(M + 63) / 64, 256, 0, stream>>>(g, x, fanin_w, fanin_b, (float*)d_out, M);
}

// Round 7
// 266.452 us; speedup vs baseline: 1.4384x; 1.1229x over previous
//
#include <hip/hip_runtime.h>
#include <hip/hip_bf16.h>
#include <cstdint>

#define N_TOK 744
#define NP    768           // padded token count
#define DW    128           // d_model
#define NH    8

typedef __attribute__((ext_vector_type(4))) float f32x4;
typedef __attribute__((ext_vector_type(4))) unsigned int u32x4;
typedef __attribute__((ext_vector_type(8))) __bf16 bf16x8;
typedef __attribute__((ext_vector_type(4))) __bf16 bf16x4;

__device__ __forceinline__ unsigned int sadu16(unsigned int a, unsigned int b, unsigned int c) {
    unsigned int d;
    asm("v_sad_u16 %0, %1, %2, %3" : "=v"(d) : "v"(a), "v"(b), "v"(c));
    return d;
}

// ---------------- Z init: Z = 1.0 (appended zero-logit contributes exp(0)=1) -------
__global__ void k_zinit(float* Z, int n) {
    int i = blockIdx.x * 256 + threadIdx.x;
    if (i < n) Z[i] = 1.0f;
}

// ---------------- QV projection: v = x @ wqv_w^T + b, routed to q / vf_t / vb_t ----
__global__ __launch_bounds__(256) void k_proj(
    const float* __restrict__ x, const float* __restrict__ wqv_w,
    const float* __restrict__ wqv_b,
    float* __restrict__ qbuf, __bf16* __restrict__ vf_t, __bf16* __restrict__ vb_t,
    int M)
{
    int tid = threadIdx.x;
    int l = tid & 63, wv = tid >> 6;
    int lr = l & 15, lg = l >> 4;
    int mbase = blockIdx.y * 64 + wv * 16;
    int c0 = blockIdx.x * 64;
    f32x4 acc[4] = {};
    for (int kk = 0; kk < 128; kk += 32) {
        int ka = kk + lg * 8;
        int ra = mbase + lr; if (ra >= M) ra = 0;   // clamp, store-guarded
        const float* ap = x + (size_t)ra * DW + ka;
        float a0[8];
        *(f32x4*)a0 = *(const f32x4*)ap; *(f32x4*)(a0 + 4) = *(const f32x4*)(ap + 4);
        bf16x8 af;
        for (int j = 0; j < 8; j++) af[j] = (__bf16)a0[j];
        for (int ct = 0; ct < 4; ct++) {
            int cb = c0 + ct * 16 + lr;
            const float* bp = wqv_w + (size_t)cb * DW + ka;
            float b0[8];
            *(f32x4*)b0 = *(const f32x4*)bp; *(f32x4*)(b0 + 4) = *(const f32x4*)(bp + 4);
            bf16x8 bfr;
            for (int j = 0; j < 8; j++) bfr[j] = (__bf16)b0[j];
            acc[ct] = __builtin_amdgcn_mfma_f32_16x16x32_bf16(af, bfr, acc[ct], 0, 0, 0);
        }
    }
    for (int ct = 0; ct < 4; ct++) {
        int c = c0 + ct * 16 + lr;
        int hd = c >> 7, wi = c & 127;
        float bias = wqv_b[c];
        for (int j = 0; j < 4; j++) {
            int r = mbase + lg * 4 + j;
            if (r >= M) continue;
            int b = r / N_TOK, s = r % N_TOK;
            float val = acc[ct][j] + bias;
            if (hd < 8) {
                qbuf[(((size_t)b * NH + hd) * NP + s) * DW + wi] = val;
            } else if (hd < 16) {
                vf_t[(((size_t)b * NH + (hd - 8)) * DW + wi) * NP + s] = (__bf16)val;
            } else {
                vb_t[(((size_t)b * NH + (hd - 16)) * DW + wi) * NP + s] = (__bf16)val;
            }
        }
    }
}

// ---------------- L1 scores via packed v_sad_u16 fixed point -----------------------
// u = (v + 2.0) * 2^14  (RN via +0.5 then trunc); two w's per u32.
__global__ __launch_bounds__(256) void k_scores(
    const float* __restrict__ qbuf, const float* __restrict__ x,
    const float* __restrict__ wk,
    __bf16* __restrict__ e1, __bf16* __restrict__ e2, float* __restrict__ Z)
{
    __shared__ unsigned int qt[16][132];   // [w-pair][row]
    __shared__ unsigned int kt[16][132];
    int bh = blockIdx.z; int b = bh >> 3, h = bh & 7;
    int s0 = blockIdx.y * 128, d0 = blockIdx.x * 128;
    int tid = threadIdx.x;
    int ty = tid >> 4, tx = tid & 15;      // 16x16 threads, each 8x8 outputs
    const float* qbase = qbuf + (size_t)bh * NP * DW;
    const float* xbase = x + (size_t)b * N_TOK * DW;
    const float* wkh = wk + h * DW;
    unsigned int acc[8][8] = {};
    int lp = tid & 15;          // pair index 0..15 within chunk
    int lr0 = tid >> 4;         // row base 0..15
    for (int wc = 0; wc < 128; wc += 32) {
        float wk0 = wkh[wc + 2 * lp], wk1 = wkh[wc + 2 * lp + 1];
        #pragma unroll
        for (int pass = 0; pass < 8; pass++) {
            int r = pass * 16 + lr0;
            const float* qp = qbase + (size_t)(s0 + r) * DW + wc + 2 * lp;
            float q0 = qp[0], q1 = qp[1];
            unsigned int uq0 = (unsigned int)__builtin_fmaf(q0, 16384.0f, 32768.5f);
            unsigned int uq1 = (unsigned int)__builtin_fmaf(q1, 16384.0f, 32768.5f);
            qt[lp][r] = uq0 | (uq1 << 16);
            int d = d0 + r;
            float x0 = 0.0f, x1 = 0.0f;
            if (d < N_TOK) {
                const float* xp = xbase + (size_t)d * DW + wc + 2 * lp;
                x0 = xp[0]; x1 = xp[1];
            }
            unsigned int uk0 = (unsigned int)__builtin_fmaf(x0 * wk0, 16384.0f, 32768.5f);
            unsigned int uk1 = (unsigned int)__builtin_fmaf(x1 * wk1, 16384.0f, 32768.5f);
            kt[lp][r] = uk0 | (uk1 << 16);
        }
        __syncthreads();
        #pragma unroll
        for (int wp = 0; wp < 16; wp++) {
            unsigned int qv[8], kv[8];
            *(u32x4*)&qv[0] = *(const u32x4*)&qt[wp][ty * 8];
            *(u32x4*)&qv[4] = *(const u32x4*)&qt[wp][ty * 8 + 4];
            *(u32x4*)&kv[0] = *(const u32x4*)&kt[wp][tx * 8];
            *(u32x4*)&kv[4] = *(const u32x4*)&kt[wp][tx * 8 + 4];
            #pragma unroll
            for (int i = 0; i < 8; i++)
                #pragma unroll
                for (int j = 0; j < 8; j++)
                    acc[i][j] = sadu16(qv[i], kv[j], acc[i][j]);
        }
        __syncthreads();
    }
    const float SS = 0.08838834764831845f / 16384.0f;
    float e[8][8]; float colsum[8] = {};
    int sb = s0 + ty * 8, db = d0 + tx * 8;
    #pragma unroll
    for (int i = 0; i < 8; i++)
        #pragma unroll
        for (int j = 0; j < 8; j++) {
            float ev = ((sb + i) < N_TOK && (db + j) < N_TOK)
                       ? __expf(-(float)acc[i][j] * SS) : 0.0f;
            e[i][j] = ev; colsum[j] += ev;
        }
    size_t ebase = (size_t)bh * NP * NP;
    #pragma unroll
    for (int i = 0; i < 8; i++) {
        bf16x8 v;
        #pragma unroll
        for (int j = 0; j < 8; j++) v[j] = (__bf16)e[i][j];
        *(bf16x8*)&e2[ebase + (size_t)(sb + i) * NP + db] = v;
    }
    #pragma unroll
    for (int j = 0; j < 8; j++) {
        bf16x8 v;
        #pragma unroll
        for (int i = 0; i < 8; i++) v[i] = (__bf16)e[i][j];
        *(bf16x8*)&e1[ebase + (size_t)(db + j) * NP + sb] = v;
    }
    float* red = (float*)&qt[0][0];
    #pragma unroll
    for (int j = 0; j < 8; j++) red[ty * 128 + tx * 8 + j] = colsum[j];
    __syncthreads();
    if (tid < 128) {
        float z = 0;
        #pragma unroll
        for (int r = 0; r < 16; r++) z += red[r * 128 + tid];
        atomicAdd(&Z[(size_t)bh * NP + d0 + tid], z);
    }
}

// ---------------- fold 1/Z[token] into Vb (in place) ------------------------------
__global__ void k_scalevb(__bf16* vb_t, const float* __restrict__ Z, long total8)
{
    long idx = (long)blockIdx.x * blockDim.x + threadIdx.x;
    if (idx >= total8) return;
    size_t base = (size_t)idx * 8;
    int s = (int)(base % NP);
    int bh = (int)((base / NP) / DW);
    bf16x8 v = *(bf16x8*)&vb_t[base];
    const float* Zp = Z + (size_t)bh * NP + s;
    bf16x8 o;
    #pragma unroll
    for (int i = 0; i < 8; i++) o[i] = (__bf16)((float)v[i] / Zp[i]);
    *(bf16x8*)&vb_t[base] = o;
}

// ---------------- attention apply: LDS double-buffered pipelined GEMMs -------------
// Per K-step-64: stage E1[32][64], E2[32][64], VF[128][64], VB[128][64] via
// global_load_lds w=16 (40 x 1KB units, 10/wave), XOR-swizzled source (T2/m173),
// counted vmcnt(10) + raw barriers (never drain in loop).
__global__ __launch_bounds__(256) void k_apply(
    const __bf16* __restrict__ e1, const __bf16* __restrict__ e2,
    const __bf16* __restrict__ vf_t, const __bf16* __restrict__ vb_t,
    const float* __restrict__ Z, float* __restrict__ y0f, float* __restrict__ y0b)
{
    __shared__ __align__(16) char smem[2][40960];   // 80 KB: 2 blocks/CU
    int bh = blockIdx.y;
    int tid = threadIdx.x;
    int l = tid & 63, wv = tid >> 6;
    int lr = l & 15, lg = l >> 4;
    int m0b = blockIdx.x * 32;
    int m0 = m0b + (wv & 1) * 16;
    bool doF = (wv < 2);

    const char* e1b = (const char*)e1 + 2 * ((size_t)bh * NP * NP + (size_t)m0b * NP);
    const char* e2b = (const char*)e2 + 2 * ((size_t)bh * NP * NP + (size_t)m0b * NP);
    const char* vfb = (const char*)vf_t + 2 * ((size_t)bh * DW * NP);
    const char* vbb = (const char*)vb_t + 2 * ((size_t)bh * DW * NP);
    unsigned int swz = (16u * (l & 7)) ^ (((unsigned)(l >> 3)) << 4);  // pre-swizzled source
    size_t rowoff = (size_t)(l >> 3) * (NP * 2);                       // row within 8-row unit

    // stage one K-step (kk elements) into buffer bi: this wave's 10 of 40 units
    #define STAGE(bi, kk) do {                                                        \
        for (int u = wv; u < 40; u += 4) {                                            \
            char* lp = &smem[bi][u * 1024];                                           \
            const char* gp;                                                           \
            if (u < 4)       gp = e1b + (size_t)(8 * u) * (NP * 2);                   \
            else if (u < 8)  gp = e2b + (size_t)(8 * (u - 4)) * (NP * 2);             \
            else if (u < 24) gp = vfb + (size_t)(8 * (u - 8)) * (NP * 2);             \
            else             gp = vbb + (size_t)(8 * (u - 24)) * (NP * 2);            \
            gp += rowoff + (size_t)(kk) * 2 + swz;                                    \
            __builtin_amdgcn_global_load_lds(                                         \
                (const __attribute__((address_space(1))) void*)gp,                    \
                (__attribute__((address_space(3))) void*)lp, 16, 0, 0);               \
        }                                                                             \
    } while (0)

    const char* eL0 = &smem[0][doF ? 0 : 4096];
    const char* vL0 = &smem[0][doF ? 8192 : 24576];
    int mloc = (wv & 1) * 16 + lr;          // E-tile local row
    unsigned int rswz = ((unsigned)(lr & 7)) << 4;

    f32x4 acc[8] = {};
    STAGE(0, 0);
    STAGE(1, 64);
    for (int t = 0; t < 12; t++) {
        if (t < 11) asm volatile("s_waitcnt vmcnt(10)" ::: "memory");
        else        asm volatile("s_waitcnt vmcnt(0)" ::: "memory");
        __builtin_amdgcn_s_barrier();
        const char* eL = eL0 + (t & 1) * 40960;
        const char* vL = vL0 + (t & 1) * 40960;
        #pragma unroll
        for (int ph = 0; ph < 2; ph++) {
            unsigned int csw = (ph * 64 + lg * 16) ^ rswz;
            bf16x8 a = *(const bf16x8*)(eL + mloc * 128 + csw);
            #pragma unroll
            for (int ct = 0; ct < 8; ct++) {
                bf16x8 bfr = *(const bf16x8*)(vL + (ct * 16 + lr) * 128 + csw);
                acc[ct] = __builtin_amdgcn_mfma_f32_16x16x32_bf16(a, bfr, acc[ct], 0, 0, 0);
            }
        }
        __builtin_amdgcn_s_barrier();
        if (t + 2 < 12) STAGE(t & 1, (t + 2) * 64);
    }
    #undef STAGE

    float sc[4];
    #pragma unroll
    for (int j = 0; j < 4; j++)
        sc[j] = doF ? (1.0f / Z[(size_t)bh * NP + m0 + lg * 4 + j]) : 1.0f;
    float* yb = (doF ? y0f : y0b) + ((size_t)bh * NP + m0) * DW;
    #pragma unroll
    for (int ct = 0; ct < 8; ct++)
        #pragma unroll
        for (int j = 0; j < 4; j++)
            yb[(size_t)(lg * 4 + j) * DW + ct * 16 + lr] = sc[j] * acc[ct][j];
}

// ---------------- h-reduce + qgelu -> g (bf16) -------------------------------------
__global__ __launch_bounds__(256) void k_fin1(
    const float* __restrict__ y0f, const float* __restrict__ y0b,
    __bf16* __restrict__ g, int M)
{
    int idx = blockIdx.x * 256 + threadIdx.x;  // one per 4 cols
    int r = idx >> 5;
    int c = (idx & 31) * 4;
    if (r >= M) return;
    int b = r / N_TOK, s = r % N_TOK;
    f32x4 sum = {};
    size_t base = ((size_t)b * NH * NP + s) * DW + c;
    #pragma unroll
    for (int h = 0; h < NH; h++) {
        sum += *(const f32x4*)&y0f[base + (size_t)h * NP * DW];
        sum += *(const f32x4*)&y0b[base + (size_t)h * NP * DW];
    }
    bf16x4 o;
    #pragma unroll
    for (int i = 0; i < 4; i++) {
        float z = sum[i] + 4.5f;
        float gv = z / (1.0f + __expf(-1.702f * z)) - 4.5f;
        o[i] = (__bf16)gv;
    }
    *(bf16x4*)&g[(size_t)r * DW + c] = o;
}

// ---------------- fanin MFMA GEMM + residual ---------------------------------------
__global__ __launch_bounds__(256) void k_fin2(
    const __bf16* __restrict__ g, const float* __restrict__ x,
    const float* __restrict__ fanin_w, const float* __restrict__ fanin_b,
    float* __restrict__ out, int M)
{
    int tid = threadIdx.x;
    int l = tid & 63, wv = tid >> 6;
    int lr = l & 15, lg = l >> 4;
    int m0 = blockIdx.x * 64 + wv * 16;
    f32x4 acc[8] = {};
    int ar = m0 + lr; if (ar >= M) ar = M - 1;
    const __bf16* gp = g + (size_t)ar * DW;
    for (int kk = 0; kk < 128; kk += 32) {
        int ko = kk + lg * 8;
        bf16x8 a = *(const bf16x8*)(gp + ko);
        #pragma unroll
        for (int ct = 0; ct < 8; ct++) {
            const float* wp = fanin_w + (size_t)(ct * 16 + lr) * DW + ko;
            float w0[8];
            *(f32x4*)w0 = *(const f32x4*)wp; *(f32x4*)(w0 + 4) = *(const f32x4*)(wp + 4);
            bf16x8 bfr;
            #pragma unroll
            for (int j2 = 0; j2 < 8; j2++) bfr[j2] = (__bf16)w0[j2];
            acc[ct] = __builtin_amdgcn_mfma_f32_16x16x32_bf16(a, bfr, acc[ct], 0, 0, 0);
        }
    }
    #pragma unroll
    for (int ct = 0; ct < 8; ct++) {
        int c = ct * 16 + lr;
        float fb = fanin_b[c];
        #pragma unroll
        for (int j = 0; j < 4; j++) {
            int r = m0 + lg * 4 + j;
            if (r < M) out[(size_t)r * DW + c] = x[(size_t)r * DW + c] + acc[ct][j] + fb;
        }
    }
}

extern "C" void kernel_launch(void* const* d_in, const int* in_sizes, int n_in,
                              void* d_out, int out_size, void* d_ws, size_t ws_size,
                              hipStream_t stream)
{
    const float* x       = (const float*)d_in[0];
    const float* wk      = (const float*)d_in[1];
    const float* wqv_w   = (const float*)d_in[2];
    const float* wqv_b   = (const float*)d_in[3];
    const float* fanin_w = (const float*)d_in[4];
    const float* fanin_b = (const float*)d_in[5];
    int B = in_sizes[0] / (N_TOK * DW);
    int M = B * N_TOK;

    char* ws = (char*)d_ws;
    size_t off = 0;
    float*  qbuf = (float*)(ws + off);  off += (size_t)B * NH * NP * DW * 4;  // also y0f
    __bf16* vf_t = (__bf16*)(ws + off); off += (size_t)B * NH * DW * NP * 2;  // also g
    __bf16* vb_t = (__bf16*)(ws + off); off += (size_t)B * NH * DW * NP * 2;
    __bf16* e1   = (__bf16*)(ws + off); off += (size_t)B * NH * NP * NP * 2;
    __bf16* e2   = (__bf16*)(ws + off); off += (size_t)B * NH * NP * NP * 2;
    float*  Z    = (float*)(ws + off);  off += (size_t)B * NH * NP * 4;
    float*  y0b  = (float*)(ws + off);  off += (size_t)B * NH * NP * DW * 4;
    if (off > ws_size) return;
    float*  y0f = qbuf;          // qbuf dead after k_scores
    __bf16* g   = vf_t;          // vf_t dead after k_apply

    int zn = B * NH * NP;
    k_zinit<<<(zn + 255) / 256, 256, 0, stream>>>(Z, zn);

    dim3 gp(3072 / 64, (M + 63) / 64);
    k_proj<<<gp, 256, 0, stream>>>(x, wqv_w, wqv_b, qbuf, vf_t, vb_t, M);

    dim3 gs(NP / 128, NP / 128, B * NH);
    k_scores<<<gs, 256, 0, stream>>>(qbuf, x, wk, e1, e2, Z);

    long total8 = (long)B * NH * DW * NP / 8;
    k_scalevb<<<(int)((total8 + 255) / 256), 256, 0, stream>>>(vb_t, Z, total8);

    dim3 ga(NP / 32, B * NH);
    k_apply<<<ga, 256, 0, stream>>>(e1, e2, vf_t, vb_t, Z, y0f, y0b);

    int f1blocks = (M * (DW / 4) + 255) / 256;
    k_fin1<<<f1blocks, 256, 0, stream>>>(y0f, y0b, g, M);

    k_fin2<<<(M + 63) / 64, 256, 0, stream>>>(g, x, fanin_w, fanin_b, (float*)d_out, M);
}

// Round 9
// 235.457 us; speedup vs baseline: 1.6278x; 1.1316x over previous
//
#include <hip/hip_runtime.h>
#include <hip/hip_bf16.h>
#include <cstdint>

#define N_TOK 744
#define NP    768           // padded token count
#define DW    128           // d_model
#define NH    8

typedef __attribute__((ext_vector_type(4))) float f32x4;
typedef __attribute__((ext_vector_type(4))) unsigned int u32x4;
typedef __attribute__((ext_vector_type(8))) __bf16 bf16x8;
typedef __attribute__((ext_vector_type(4))) __bf16 bf16x4;

__device__ __forceinline__ unsigned int sadu8(unsigned int a, unsigned int b, unsigned int c) {
    unsigned int d;
    asm("v_sad_u8 %0, %1, %2, %3" : "=v"(d) : "v"(a), "v"(b), "v"(c));
    return d;
}

// ---------------- Z init: Z = 1.0 (appended zero-logit contributes exp(0)=1) -------
__global__ void k_zinit(float* Z, int n) {
    int i = blockIdx.x * 256 + threadIdx.x;
    if (i < n) Z[i] = 1.0f;
}

// ---------------- QV projection -----------------------------------------------------
// q blocks (c0<1024): D = X·W^T (rows=s)   -> f32 coalesced stores to qbuf
// v blocks: D = W·X^T (rows=c, cols=s)     -> bf16 16-lane-contiguous stores to v*_t
__global__ __launch_bounds__(256) void k_proj(
    const float* __restrict__ x, const float* __restrict__ wqv_w,
    const float* __restrict__ wqv_b,
    float* __restrict__ qbuf, __bf16* __restrict__ vf_t, __bf16* __restrict__ vb_t,
    int M)
{
    int tid = threadIdx.x;
    int l = tid & 63, wv = tid >> 6;
    int lr = l & 15, lg = l >> 4;
    int mbase = blockIdx.y * 64 + wv * 16;
    int c0 = blockIdx.x * 64;
    bool vpath = (c0 >= 1024);
    f32x4 acc[4] = {};
    for (int kk = 0; kk < 128; kk += 32) {
        int ka = kk + lg * 8;
        int ra = mbase + lr; if (ra >= M) ra = 0;   // clamp, store-guarded
        const float* ap = x + (size_t)ra * DW + ka;
        float a0[8];
        *(f32x4*)a0 = *(const f32x4*)ap; *(f32x4*)(a0 + 4) = *(const f32x4*)(ap + 4);
        bf16x8 af;
        for (int j = 0; j < 8; j++) af[j] = (__bf16)a0[j];
        for (int ct = 0; ct < 4; ct++) {
            int cb = c0 + ct * 16 + lr;
            const float* bp = wqv_w + (size_t)cb * DW + ka;
            float b0[8];
            *(f32x4*)b0 = *(const f32x4*)bp; *(f32x4*)(b0 + 4) = *(const f32x4*)(bp + 4);
            bf16x8 bfr;
            for (int j = 0; j < 8; j++) bfr[j] = (__bf16)b0[j];
            if (vpath) acc[ct] = __builtin_amdgcn_mfma_f32_16x16x32_bf16(bfr, af, acc[ct], 0, 0, 0);
            else       acc[ct] = __builtin_amdgcn_mfma_f32_16x16x32_bf16(af, bfr, acc[ct], 0, 0, 0);
        }
    }
    if (!vpath) {
        // rows = s (lg*4+j), cols = c (lr); all cols are q (hd<8)
        for (int ct = 0; ct < 4; ct++) {
            int c = c0 + ct * 16 + lr;
            int hd = c >> 7, wi = c & 127;
            float bias = wqv_b[c];
            for (int j = 0; j < 4; j++) {
                int r = mbase + lg * 4 + j;
                if (r >= M) continue;
                int b = r / N_TOK, s = r % N_TOK;
                qbuf[(((size_t)b * NH + hd) * NP + s) * DW + wi] = acc[ct][j] + bias;
            }
        }
    } else {
        // rows = c (lg*4+j), cols = s (lr): contiguous-lane bf16 stores
        int r = mbase + lr;
        bool rok = (r < M);
        int b = rok ? (r / N_TOK) : 0;
        int st = rok ? (r % N_TOK) : 0;
        int hd0 = c0 >> 7;                        // uniform for the block
        __bf16* dst0 = (hd0 < 16) ? vf_t : vb_t;
        int hh = (hd0 < 16) ? (hd0 - 8) : (hd0 - 16);
        for (int ct = 0; ct < 4; ct++) {
            int cb = c0 + ct * 16 + lg * 4;
            f32x4 bias4 = *(const f32x4*)(wqv_b + cb);
            for (int j = 0; j < 4; j++) {
                int wi = (cb + j) & 127;
                if (rok)
                    dst0[(((size_t)b * NH + hh) * DW + wi) * NP + st] =
                        (__bf16)(acc[ct][j] + bias4[j]);
            }
        }
    }
}

// ---------------- L1 scores via packed v_sad_u8 fixed point ------------------------
// u = round((clamp(v,±0.992) + 1.0) * 128); four w's per u32.
// sum_w |uq-uk| = 128 * sum_w |q-k|
__global__ __launch_bounds__(256) void k_scores(
    const float* __restrict__ qbuf, const float* __restrict__ x,
    const float* __restrict__ wk,
    __bf16* __restrict__ e1, __bf16* __restrict__ e2, float* __restrict__ Z)
{
    __shared__ unsigned int qt[32][132];   // [w-group(4w)][row], 528B rows (16B align)
    __shared__ unsigned int kt[32][132];
    int bh = blockIdx.z; int b = bh >> 3, h = bh & 7;
    int s0 = blockIdx.y * 128, d0 = blockIdx.x * 128;
    int tid = threadIdx.x;
    int ty = tid >> 4, tx = tid & 15;      // 16x16 threads, each 8x8 outputs
    const float* qbase = qbuf + (size_t)bh * NP * DW;
    const float* xbase = x + (size_t)b * N_TOK * DW;
    const float* wkh = wk + h * DW;

    // one-shot staging of the full 128-w strip
    int cg = tid & 31;                      // u32 group (4 w's)
    int r0 = tid >> 5;                      // 0..7
    float w4[4];
    *(f32x4*)w4 = *(const f32x4*)(wkh + 4 * cg);
    const float CL = 0.9921875f;
    #pragma unroll
    for (int pass = 0; pass < 16; pass++) {
        int r = pass * 8 + r0;
        f32x4 qv4 = *(const f32x4*)(qbase + (size_t)(s0 + r) * DW + 4 * cg);
        unsigned int uq = 0;
        #pragma unroll
        for (int e = 0; e < 4; e++) {
            float v = fminf(fmaxf(qv4[e], -CL), CL);
            unsigned int u = (unsigned int)__builtin_fmaf(v, 128.0f, 128.5f);
            uq |= u << (8 * e);
        }
        qt[cg][r] = uq;
        int d = d0 + r;
        f32x4 xv4 = {};
        if (d < N_TOK) xv4 = *(const f32x4*)(xbase + (size_t)d * DW + 4 * cg);
        unsigned int uk = 0;
        #pragma unroll
        for (int e = 0; e < 4; e++) {
            float v = fminf(fmaxf(xv4[e] * w4[e], -CL), CL);
            unsigned int u = (unsigned int)__builtin_fmaf(v, 128.0f, 128.5f);
            uk |= u << (8 * e);
        }
        kt[cg][r] = uk;
    }
    __syncthreads();

    unsigned int acc[8][8] = {};
    #pragma unroll 4
    for (int g = 0; g < 32; g++) {
        unsigned int qv[8], kv[8];
        *(u32x4*)&qv[0] = *(const u32x4*)&qt[g][ty * 8];
        *(u32x4*)&qv[4] = *(const u32x4*)&qt[g][ty * 8 + 4];
        *(u32x4*)&kv[0] = *(const u32x4*)&kt[g][tx * 8];
        *(u32x4*)&kv[4] = *(const u32x4*)&kt[g][tx * 8 + 4];
        #pragma unroll
        for (int i = 0; i < 8; i++)
            #pragma unroll
            for (int j = 0; j < 8; j++)
                acc[i][j] = sadu8(qv[i], kv[j], acc[i][j]);
    }

    const float SS = 0.08838834764831845f / 128.0f;
    float e[8][8]; float colsum[8] = {};
    int sb = s0 + ty * 8, db = d0 + tx * 8;
    #pragma unroll
    for (int i = 0; i < 8; i++)
        #pragma unroll
        for (int j = 0; j < 8; j++) {
            float ev = ((sb + i) < N_TOK && (db + j) < N_TOK)
                       ? __expf(-(float)acc[i][j] * SS) : 0.0f;
            e[i][j] = ev; colsum[j] += ev;
        }
    size_t ebase = (size_t)bh * NP * NP;
    #pragma unroll
    for (int i = 0; i < 8; i++) {
        bf16x8 v;
        #pragma unroll
        for (int j = 0; j < 8; j++) v[j] = (__bf16)e[i][j];
        *(bf16x8*)&e2[ebase + (size_t)(sb + i) * NP + db] = v;
    }
    #pragma unroll
    for (int j = 0; j < 8; j++) {
        bf16x8 v;
        #pragma unroll
        for (int i = 0; i < 8; i++) v[i] = (__bf16)e[i][j];
        *(bf16x8*)&e1[ebase + (size_t)(db + j) * NP + sb] = v;
    }
    __syncthreads();                       // qt reused as reduce scratch
    float* red = (float*)&qt[0][0];
    #pragma unroll
    for (int j = 0; j < 8; j++) red[ty * 128 + tx * 8 + j] = colsum[j];
    __syncthreads();
    if (tid < 128) {
        float z = 0;
        #pragma unroll
        for (int r = 0; r < 16; r++) z += red[r * 128 + tid];
        atomicAdd(&Z[(size_t)bh * NP + d0 + tid], z);
    }
}

// ---------------- fold 1/Z[token] into Vb (in place) ------------------------------
__global__ void k_scalevb(__bf16* vb_t, const float* __restrict__ Z, long total8)
{
    long idx = (long)blockIdx.x * blockDim.x + threadIdx.x;
    if (idx >= total8) return;
    size_t base = (size_t)idx * 8;
    int s = (int)(base % NP);
    int bh = (int)((base / NP) / DW);
    bf16x8 v = *(bf16x8*)&vb_t[base];
    const float* Zp = Z + (size_t)bh * NP + s;
    bf16x8 o;
    #pragma unroll
    for (int i = 0; i < 8; i++) o[i] = (__bf16)((float)v[i] / Zp[i]);
    *(bf16x8*)&vb_t[base] = o;
}

// ---------------- attention apply: LDS double-buffered pipelined GEMMs -------------
__global__ __launch_bounds__(256) void k_apply(
    const __bf16* __restrict__ e1, const __bf16* __restrict__ e2,
    const __bf16* __restrict__ vf_t, const __bf16* __restrict__ vb_t,
    const float* __restrict__ Z, __bf16* __restrict__ y0f, __bf16* __restrict__ y0b)
{
    __shared__ __align__(16) char smem[2][40960];   // 80 KB: 2 blocks/CU
    int bh = blockIdx.y;
    int tid = threadIdx.x;
    int l = tid & 63, wv = tid >> 6;
    int lr = l & 15, lg = l >> 4;
    int m0b = blockIdx.x * 32;
    int m0 = m0b + (wv & 1) * 16;
    bool doF = (wv < 2);

    const char* e1b = (const char*)e1 + 2 * ((size_t)bh * NP * NP + (size_t)m0b * NP);
    const char* e2b = (const char*)e2 + 2 * ((size_t)bh * NP * NP + (size_t)m0b * NP);
    const char* vfb = (const char*)vf_t + 2 * ((size_t)bh * DW * NP);
    const char* vbb = (const char*)vb_t + 2 * ((size_t)bh * DW * NP);
    unsigned int swz = (16u * (l & 7)) ^ (((unsigned)(l >> 3)) << 4);  // pre-swizzled source
    size_t rowoff = (size_t)(l >> 3) * (NP * 2);                       // row within 8-row unit

    #define STAGE(bi, kk) do {                                                        \
        for (int u = wv; u < 40; u += 4) {                                            \
            char* lp = &smem[bi][u * 1024];                                           \
            const char* gp;                                                           \
            if (u < 4)       gp = e1b + (size_t)(8 * u) * (NP * 2);                   \
            else if (u < 8)  gp = e2b + (size_t)(8 * (u - 4)) * (NP * 2);             \
            else if (u < 24) gp = vfb + (size_t)(8 * (u - 8)) * (NP * 2);             \
            else             gp = vbb + (size_t)(8 * (u - 24)) * (NP * 2);            \
            gp += rowoff + (size_t)(kk) * 2 + swz;                                    \
            __builtin_amdgcn_global_load_lds(                                         \
                (const __attribute__((address_space(1))) void*)gp,                    \
                (__attribute__((address_space(3))) void*)lp, 16, 0, 0);               \
        }                                                                             \
    } while (0)

    const char* eL0 = &smem[0][doF ? 0 : 4096];
    const char* vL0 = &smem[0][doF ? 8192 : 24576];
    int mloc = (wv & 1) * 16 + lr;
    unsigned int rswz = ((unsigned)(lr & 7)) << 4;

    f32x4 acc[8] = {};
    STAGE(0, 0);
    STAGE(1, 64);
    for (int t = 0; t < 12; t++) {
        if (t < 11) asm volatile("s_waitcnt vmcnt(10)" ::: "memory");
        else        asm volatile("s_waitcnt vmcnt(0)" ::: "memory");
        __builtin_amdgcn_s_barrier();
        const char* eL = eL0 + (t & 1) * 40960;
        const char* vL = vL0 + (t & 1) * 40960;
        #pragma unroll
        for (int ph = 0; ph < 2; ph++) {
            unsigned int csw = (ph * 64 + lg * 16) ^ rswz;
            bf16x8 a = *(const bf16x8*)(eL + mloc * 128 + csw);
            #pragma unroll
            for (int ct = 0; ct < 8; ct++) {
                bf16x8 bfr = *(const bf16x8*)(vL + (ct * 16 + lr) * 128 + csw);
                acc[ct] = __builtin_amdgcn_mfma_f32_16x16x32_bf16(a, bfr, acc[ct], 0, 0, 0);
            }
        }
        __builtin_amdgcn_s_barrier();
        if (t + 2 < 12) STAGE(t & 1, (t + 2) * 64);
    }
    #undef STAGE

    float sc[4];
    #pragma unroll
    for (int j = 0; j < 4; j++)
        sc[j] = doF ? (1.0f / Z[(size_t)bh * NP + m0 + lg * 4 + j]) : 1.0f;
    __bf16* yb = (doF ? y0f : y0b) + ((size_t)bh * NP + m0) * DW;
    #pragma unroll
    for (int ct = 0; ct < 8; ct++)
        #pragma unroll
        for (int j = 0; j < 4; j++)
            yb[(size_t)(lg * 4 + j) * DW + ct * 16 + lr] = (__bf16)(sc[j] * acc[ct][j]);
}

// ---------------- h-reduce + qgelu -> g (bf16) -------------------------------------
__global__ __launch_bounds__(256) void k_fin1(
    const __bf16* __restrict__ y0f, const __bf16* __restrict__ y0b,
    __bf16* __restrict__ g, int M)
{
    int idx = blockIdx.x * 256 + threadIdx.x;  // one per 8 cols
    int r = idx >> 4;
    int c = (idx & 15) * 8;
    if (r >= M) return;
    int b = r / N_TOK, s = r % N_TOK;
    float sum[8] = {};
    size_t base = ((size_t)b * NH * NP + s) * DW + c;
    #pragma unroll
    for (int h = 0; h < NH; h++) {
        bf16x8 vf_ = *(const bf16x8*)&y0f[base + (size_t)h * NP * DW];
        bf16x8 vb_ = *(const bf16x8*)&y0b[base + (size_t)h * NP * DW];
        #pragma unroll
        for (int i = 0; i < 8; i++) sum[i] += (float)vf_[i] + (float)vb_[i];
    }
    bf16x8 o;
    #pragma unroll
    for (int i = 0; i < 8; i++) {
        float z = sum[i] + 4.5f;
        float gv = z / (1.0f + __expf(-1.702f * z)) - 4.5f;
        o[i] = (__bf16)gv;
    }
    *(bf16x8*)&g[(size_t)r * DW + c] = o;
}

// ---------------- fanin MFMA GEMM + residual ---------------------------------------
__global__ __launch_bounds__(256) void k_fin2(
    const __bf16* __restrict__ g, const float* __restrict__ x,
    const float* __restrict__ fanin_w, const float* __restrict__ fanin_b,
    float* __restrict__ out, int M)
{
    int tid = threadIdx.x;
    int l = tid & 63, wv = tid >> 6;
    int lr = l & 15, lg = l >> 4;
    int m0 = blockIdx.x * 64 + wv * 16;
    f32x4 acc[8] = {};
    int ar = m0 + lr; if (ar >= M) ar = M - 1;
    const __bf16* gp = g + (size_t)ar * DW;
    for (int kk = 0; kk < 128; kk += 32) {
        int ko = kk + lg * 8;
        bf16x8 a = *(const bf16x8*)(gp + ko);
        #pragma unroll
        for (int ct = 0; ct < 8; ct++) {
            const float* wp = fanin_w + (size_t)(ct * 16 + lr) * DW + ko;
            float w0[8];
            *(f32x4*)w0 = *(const f32x4*)wp; *(f32x4*)(w0 + 4) = *(const f32x4*)(wp + 4);
            bf16x8 bfr;
            #pragma unroll
            for (int j2 = 0; j2 < 8; j2++) bfr[j2] = (__bf16)w0[j2];
            acc[ct] = __builtin_amdgcn_mfma_f32_16x16x32_bf16(a, bfr, acc[ct], 0, 0, 0);
        }
    }
    #pragma unroll
    for (int ct = 0; ct < 8; ct++) {
        int c = ct * 16 + lr;
        float fb = fanin_b[c];
        #pragma unroll
        for (int j = 0; j < 4; j++) {
            int r = m0 + lg * 4 + j;
            if (r < M) out[(size_t)r * DW + c] = x[(size_t)r * DW + c] + acc[ct][j] + fb;
        }
    }
}

extern "C" void kernel_launch(void* const* d_in, const int* in_sizes, int n_in,
                              void* d_out, int out_size, void* d_ws, size_t ws_size,
                              hipStream_t stream)
{
    const float* x       = (const float*)d_in[0];
    const float* wk      = (const float*)d_in[1];
    const float* wqv_w   = (const float*)d_in[2];
    const float* wqv_b   = (const float*)d_in[3];
    const float* fanin_w = (const float*)d_in[4];
    const float* fanin_b = (const float*)d_in[5];
    int B = in_sizes[0] / (N_TOK * DW);
    int M = B * N_TOK;

    char* ws = (char*)d_ws;
    size_t off = 0;
    float*  qbuf = (float*)(ws + off);  off += (size_t)B * NH * NP * DW * 4;  // also y0f
    __bf16* vf_t = (__bf16*)(ws + off); off += (size_t)B * NH * DW * NP * 2;  // also g
    __bf16* vb_t = (__bf16*)(ws + off); off += (size_t)B * NH * DW * NP * 2;
    __bf16* e1   = (__bf16*)(ws + off); off += (size_t)B * NH * NP * NP * 2;
    __bf16* e2   = (__bf16*)(ws + off); off += (size_t)B * NH * NP * NP * 2;
    float*  Z    = (float*)(ws + off);  off += (size_t)B * NH * NP * 4;
    __bf16* y0b  = (__bf16*)(ws + off); off += (size_t)B * NH * NP * DW * 2;
    if (off > ws_size) return;
    __bf16* y0f = (__bf16*)qbuf;  // qbuf dead after k_scores
    __bf16* g   = vf_t;           // vf_t dead after k_apply

    int zn = B * NH * NP;
    k_zinit<<<(zn + 255) / 256, 256, 0, stream>>>(Z, zn);

    dim3 gp(3072 / 64, (M + 63) / 64);
    k_proj<<<gp, 256, 0, stream>>>(x, wqv_w, wqv_b, qbuf, vf_t, vb_t, M);

    dim3 gs(NP / 128, NP / 128, B * NH);
    k_scores<<<gs, 256, 0, stream>>>(qbuf, x, wk, e1, e2, Z);

    long total8 = (long)B * NH * DW * NP / 8;
    k_scalevb<<<(int)((total8 + 255) / 256), 256, 0, stream>>>(vb_t, Z, total8);

    dim3 ga(NP / 32, B * NH);
    k_apply<<<ga, 256, 0, stream>>>(e1, e2, vf_t, vb_t, Z, y0f, y0b);

    int f1blocks = (M * (DW / 8) + 255) / 256;
    k_fin1<<<f1blocks, 256, 0, stream>>>(y0f, y0b, g, M);

    k_fin2<<<(M + 63) / 64, 256, 0, stream>>>(g, x, fanin_w, fanin_b, (float*)d_out, M);
}

// Round 10
// 211.316 us; speedup vs baseline: 1.8137x; 1.1142x over previous
//
#include <hip/hip_runtime.h>
#include <hip/hip_bf16.h>
#include <cstdint>

#define N_TOK 744
#define NP    768           // padded token count
#define DW    128           // d_model
#define NH    8

typedef __attribute__((ext_vector_type(4))) float f32x4;
typedef __attribute__((ext_vector_type(4))) unsigned int u32x4;
typedef __attribute__((ext_vector_type(8))) __bf16 bf16x8;
typedef __attribute__((ext_vector_type(4))) __bf16 bf16x4;

__device__ __forceinline__ unsigned int sadu8(unsigned int a, unsigned int b, unsigned int c) {
    unsigned int d;
    asm("v_sad_u8 %0, %1, %2, %3" : "=v"(d) : "v"(a), "v"(b), "v"(c));
    return d;
}

// ---------------- Z init: Z = 1.0 (appended zero-logit contributes exp(0)=1) -------
__global__ void k_zinit(float* Z, int n) {
    int i = blockIdx.x * 256 + threadIdx.x;
    if (i < n) Z[i] = 1.0f;
}

// ---------------- f32 -> bf16 conversion prepass (x -> xb zero-padded, wqv_w -> wb) -
__global__ __launch_bounds__(256) void k_cvt(
    const float* __restrict__ x, const float* __restrict__ wqv_w,
    __bf16* __restrict__ xb, __bf16* __restrict__ wb, int M, int Mp)
{
    int t = blockIdx.x * 256 + threadIdx.x;     // one per 4 elements
    int xgroups = Mp * 32;                       // Mp rows x 32 col-groups
    if (t < xgroups) {
        int r = t >> 5, c4 = (t & 31) * 4;
        f32x4 v = {};
        if (r < M) v = *(const f32x4*)(x + (size_t)r * DW + c4);
        bf16x4 o;
        #pragma unroll
        for (int i = 0; i < 4; i++) o[i] = (__bf16)v[i];
        *(bf16x4*)&xb[(size_t)r * DW + c4] = o;
    } else if (t < xgroups + 3072 * 32) {
        int t2 = t - xgroups;
        int r = t2 >> 5, c4 = (t2 & 31) * 4;
        f32x4 v = *(const f32x4*)(wqv_w + (size_t)r * DW + c4);
        bf16x4 o;
        #pragma unroll
        for (int i = 0; i < 4; i++) o[i] = (__bf16)v[i];
        *(bf16x4*)&wb[(size_t)r * DW + c4] = o;
    }
}

// ---------------- QV projection: 128x128-tile staged MFMA GEMM ---------------------
// bx = col-tile (one head each: bx<8 q, 8..15 vf, 16..23 vb), by = row-tile (tokens).
// Whole K=128 staged: Xt[128][128]bf16 + Wt[128][128]bf16 = 64KB, XOR-swizzled
// source chunk (T2/m173 both-sides rule). v-blocks swap MFMA operands so D=[c][s]
// gives coalesced transposed bf16 stores.
__global__ __launch_bounds__(256) void k_proj(
    const __bf16* __restrict__ xb, const __bf16* __restrict__ wb,
    const float* __restrict__ wqv_b,
    float* __restrict__ qbuf, __bf16* __restrict__ vf_t, __bf16* __restrict__ vb_t,
    int M)
{
    __shared__ __align__(16) char smem[65536];   // Xt [0,32K) | Wt [32K,64K)
    int bx = blockIdx.x, by = blockIdx.y;
    int tid = threadIdx.x, l = tid & 63, wv = tid >> 6;
    int lr = l & 15, lg = l >> 4;
    bool vpath = (bx >= 8);

    const char* xg = (const char*)xb + (size_t)by * 128 * 256;   // 128 rows x 256B
    const char* wg = (const char*)wb + (size_t)bx * 128 * 256;

    // stage 64 x 1KB units (16/wave); unit u: tile (u<32 ? X : W), rows 4*(u&31)..+4
    // lane l: row_in_unit = l>>4, source chunk = (l&15) ^ (row&7)  [read applies same XOR]
    #pragma unroll
    for (int u = wv; u < 64; u += 4) {
        int row = 4 * (u & 31) + (l >> 4);
        unsigned int chunk = (unsigned int)(l & 15) ^ (unsigned int)(row & 7);
        const char* gp = (u < 32 ? xg : wg) + (size_t)row * 256 + chunk * 16;
        char* lp = &smem[u * 1024];
        __builtin_amdgcn_global_load_lds(
            (const __attribute__((address_space(1))) void*)gp,
            (__attribute__((address_space(3))) void*)lp, 16, 0, 0);
    }
    asm volatile("s_waitcnt vmcnt(0)" ::: "memory");
    __builtin_amdgcn_s_barrier();

    const char* Xt = smem;
    const char* Wt = smem + 32768;
    const char* TA = vpath ? Wt : Xt;    // A-operand rows = m-dim
    const char* TB = vpath ? Xt : Wt;    // B-operand rows = n-dim
    // LDS byte(row, chunk) = row*256 + (chunk ^ (row&7))*16

    f32x4 acc[2][8] = {};
    #pragma unroll
    for (int kk = 0; kk < 4; kk++) {                 // K-chunk: chunk index cA = kk*4+lg
        int cA = kk * 4 + lg;
        bf16x8 a[2];
        #pragma unroll
        for (int mr = 0; mr < 2; mr++) {
            int row = wv * 32 + mr * 16 + lr;
            a[mr] = *(const bf16x8*)(TA + row * 256 + (cA ^ (row & 7)) * 16);
        }
        #pragma unroll
        for (int nc = 0; nc < 8; nc++) {
            int row = nc * 16 + lr;
            bf16x8 bfr = *(const bf16x8*)(TB + row * 256 + (cA ^ (row & 7)) * 16);
            acc[0][nc] = __builtin_amdgcn_mfma_f32_16x16x32_bf16(a[0], bfr, acc[0][nc], 0, 0, 0);
            acc[1][nc] = __builtin_amdgcn_mfma_f32_16x16x32_bf16(a[1], bfr, acc[1][nc], 0, 0, 0);
        }
    }

    if (!vpath) {
        // D[s][c]: rows = tokens, cols = c; hd = bx uniform
        int hd = bx;
        #pragma unroll
        for (int nc = 0; nc < 8; nc++) {
            int wi = nc * 16 + lr;
            float bias = wqv_b[bx * 128 + wi];
            #pragma unroll
            for (int mr = 0; mr < 2; mr++)
                #pragma unroll
                for (int j = 0; j < 4; j++) {
                    int r = by * 128 + wv * 32 + mr * 16 + lg * 4 + j;
                    if (r >= M) continue;
                    int b = r / N_TOK, s = r % N_TOK;
                    qbuf[(((size_t)b * NH + hd) * NP + s) * DW + wi] = acc[mr][nc][j] + bias;
                }
        }
    } else {
        // D[c][s]: rows = c, cols = tokens; 16-lane-contiguous bf16 stores
        __bf16* dst0 = (bx < 16) ? vf_t : vb_t;
        int hh = (bx < 16) ? (bx - 8) : (bx - 16);
        #pragma unroll
        for (int mr = 0; mr < 2; mr++)
            #pragma unroll
            for (int j = 0; j < 4; j++) {
                int wi = wv * 32 + mr * 16 + lg * 4 + j;
                float bias = wqv_b[bx * 128 + wi];
                #pragma unroll
                for (int nc = 0; nc < 8; nc++) {
                    int r = by * 128 + nc * 16 + lr;
                    if (r >= M) continue;
                    int b = r / N_TOK, st = r % N_TOK;
                    dst0[(((size_t)b * NH + hh) * DW + wi) * NP + st] =
                        (__bf16)(acc[mr][nc][j] + bias);
                }
            }
    }
}

// ---------------- L1 scores via packed v_sad_u8 fixed point ------------------------
// u = round((clamp(v,±0.992) + 1.0) * 128); four w's per u32.
// sum_w |uq-uk| = 128 * sum_w |q-k|
__global__ __launch_bounds__(256) void k_scores(
    const float* __restrict__ qbuf, const float* __restrict__ x,
    const float* __restrict__ wk,
    __bf16* __restrict__ e1, __bf16* __restrict__ e2, float* __restrict__ Z)
{
    __shared__ unsigned int qt[32][132];   // [w-group(4w)][row], 528B rows (16B align)
    __shared__ unsigned int kt[32][132];
    int bh = blockIdx.z; int b = bh >> 3, h = bh & 7;
    int s0 = blockIdx.y * 128, d0 = blockIdx.x * 128;
    int tid = threadIdx.x;
    int ty = tid >> 4, tx = tid & 15;      // 16x16 threads, each 8x8 outputs
    const float* qbase = qbuf + (size_t)bh * NP * DW;
    const float* xbase = x + (size_t)b * N_TOK * DW;
    const float* wkh = wk + h * DW;

    // one-shot staging of the full 128-w strip
    int cg = tid & 31;                      // u32 group (4 w's)
    int r0 = tid >> 5;                      // 0..7
    float w4[4];
    *(f32x4*)w4 = *(const f32x4*)(wkh + 4 * cg);
    const float CL = 0.9921875f;
    #pragma unroll
    for (int pass = 0; pass < 16; pass++) {
        int r = pass * 8 + r0;
        f32x4 qv4 = *(const f32x4*)(qbase + (size_t)(s0 + r) * DW + 4 * cg);
        unsigned int uq = 0;
        #pragma unroll
        for (int e = 0; e < 4; e++) {
            float v = fminf(fmaxf(qv4[e], -CL), CL);
            unsigned int u = (unsigned int)__builtin_fmaf(v, 128.0f, 128.5f);
            uq |= u << (8 * e);
        }
        qt[cg][r] = uq;
        int d = d0 + r;
        f32x4 xv4 = {};
        if (d < N_TOK) xv4 = *(const f32x4*)(xbase + (size_t)d * DW + 4 * cg);
        unsigned int uk = 0;
        #pragma unroll
        for (int e = 0; e < 4; e++) {
            float v = fminf(fmaxf(xv4[e] * w4[e], -CL), CL);
            unsigned int u = (unsigned int)__builtin_fmaf(v, 128.0f, 128.5f);
            uk |= u << (8 * e);
        }
        kt[cg][r] = uk;
    }
    __syncthreads();

    unsigned int acc[8][8] = {};
    #pragma unroll 4
    for (int g = 0; g < 32; g++) {
        unsigned int qv[8], kv[8];
        *(u32x4*)&qv[0] = *(const u32x4*)&qt[g][ty * 8];
        *(u32x4*)&qv[4] = *(const u32x4*)&qt[g][ty * 8 + 4];
        *(u32x4*)&kv[0] = *(const u32x4*)&kt[g][tx * 8];
        *(u32x4*)&kv[4] = *(const u32x4*)&kt[g][tx * 8 + 4];
        #pragma unroll
        for (int i = 0; i < 8; i++)
            #pragma unroll
            for (int j = 0; j < 8; j++)
                acc[i][j] = sadu8(qv[i], kv[j], acc[i][j]);
    }

    const float SS = 0.08838834764831845f / 128.0f;
    float e[8][8]; float colsum[8] = {};
    int sb = s0 + ty * 8, db = d0 + tx * 8;
    #pragma unroll
    for (int i = 0; i < 8; i++)
        #pragma unroll
        for (int j = 0; j < 8; j++) {
            float ev = ((sb + i) < N_TOK && (db + j) < N_TOK)
                       ? __expf(-(float)acc[i][j] * SS) : 0.0f;
            e[i][j] = ev; colsum[j] += ev;
        }
    size_t ebase = (size_t)bh * NP * NP;
    #pragma unroll
    for (int i = 0; i < 8; i++) {
        bf16x8 v;
        #pragma unroll
        for (int j = 0; j < 8; j++) v[j] = (__bf16)e[i][j];
        *(bf16x8*)&e2[ebase + (size_t)(sb + i) * NP + db] = v;
    }
    #pragma unroll
    for (int j = 0; j < 8; j++) {
        bf16x8 v;
        #pragma unroll
        for (int i = 0; i < 8; i++) v[i] = (__bf16)e[i][j];
        *(bf16x8*)&e1[ebase + (size_t)(db + j) * NP + sb] = v;
    }
    __syncthreads();                       // qt reused as reduce scratch
    float* red = (float*)&qt[0][0];
    #pragma unroll
    for (int j = 0; j < 8; j++) red[ty * 128 + tx * 8 + j] = colsum[j];
    __syncthreads();
    if (tid < 128) {
        float z = 0;
        #pragma unroll
        for (int r = 0; r < 16; r++) z += red[r * 128 + tid];
        atomicAdd(&Z[(size_t)bh * NP + d0 + tid], z);
    }
}

// ---------------- fold 1/Z[token] into Vb (in place) ------------------------------
__global__ void k_scalevb(__bf16* vb_t, const float* __restrict__ Z, long total8)
{
    long idx = (long)blockIdx.x * blockDim.x + threadIdx.x;
    if (idx >= total8) return;
    size_t base = (size_t)idx * 8;
    int s = (int)(base % NP);
    int bh = (int)((base / NP) / DW);
    bf16x8 v = *(bf16x8*)&vb_t[base];
    const float* Zp = Z + (size_t)bh * NP + s;
    bf16x8 o;
    #pragma unroll
    for (int i = 0; i < 8; i++) o[i] = (__bf16)((float)v[i] / Zp[i]);
    *(bf16x8*)&vb_t[base] = o;
}

// ---------------- attention apply: LDS double-buffered pipelined GEMMs -------------
__global__ __launch_bounds__(256) void k_apply(
    const __bf16* __restrict__ e1, const __bf16* __restrict__ e2,
    const __bf16* __restrict__ vf_t, const __bf16* __restrict__ vb_t,
    const float* __restrict__ Z, __bf16* __restrict__ y0f, __bf16* __restrict__ y0b)
{
    __shared__ __align__(16) char smem[2][40960];   // 80 KB: 2 blocks/CU
    int bh = blockIdx.y;
    int tid = threadIdx.x;
    int l = tid & 63, wv = tid >> 6;
    int lr = l & 15, lg = l >> 4;
    int m0b = blockIdx.x * 32;
    int m0 = m0b + (wv & 1) * 16;
    bool doF = (wv < 2);

    const char* e1b = (const char*)e1 + 2 * ((size_t)bh * NP * NP + (size_t)m0b * NP);
    const char* e2b = (const char*)e2 + 2 * ((size_t)bh * NP * NP + (size_t)m0b * NP);
    const char* vfb = (const char*)vf_t + 2 * ((size_t)bh * DW * NP);
    const char* vbb = (const char*)vb_t + 2 * ((size_t)bh * DW * NP);
    unsigned int swz = (16u * (l & 7)) ^ (((unsigned)(l >> 3)) << 4);  // pre-swizzled source
    size_t rowoff = (size_t)(l >> 3) * (NP * 2);                       // row within 8-row unit

    #define STAGE(bi, kk) do {                                                        \
        for (int u = wv; u < 40; u += 4) {                                            \
            char* lp = &smem[bi][u * 1024];                                           \
            const char* gp;                                                           \
            if (u < 4)       gp = e1b + (size_t)(8 * u) * (NP * 2);                   \
            else if (u < 8)  gp = e2b + (size_t)(8 * (u - 4)) * (NP * 2);             \
            else if (u < 24) gp = vfb + (size_t)(8 * (u - 8)) * (NP * 2);             \
            else             gp = vbb + (size_t)(8 * (u - 24)) * (NP * 2);            \
            gp += rowoff + (size_t)(kk) * 2 + swz;                                    \
            __builtin_amdgcn_global_load_lds(                                         \
                (const __attribute__((address_space(1))) void*)gp,                    \
                (__attribute__((address_space(3))) void*)lp, 16, 0, 0);               \
        }                                                                             \
    } while (0)

    const char* eL0 = &smem[0][doF ? 0 : 4096];
    const char* vL0 = &smem[0][doF ? 8192 : 24576];
    int mloc = (wv & 1) * 16 + lr;
    unsigned int rswz = ((unsigned)(lr & 7)) << 4;

    f32x4 acc[8] = {};
    STAGE(0, 0);
    STAGE(1, 64);
    for (int t = 0; t < 12; t++) {
        if (t < 11) asm volatile("s_waitcnt vmcnt(10)" ::: "memory");
        else        asm volatile("s_waitcnt vmcnt(0)" ::: "memory");
        __builtin_amdgcn_s_barrier();
        const char* eL = eL0 + (t & 1) * 40960;
        const char* vL = vL0 + (t & 1) * 40960;
        #pragma unroll
        for (int ph = 0; ph < 2; ph++) {
            unsigned int csw = (ph * 64 + lg * 16) ^ rswz;
            bf16x8 a = *(const bf16x8*)(eL + mloc * 128 + csw);
            #pragma unroll
            for (int ct = 0; ct < 8; ct++) {
                bf16x8 bfr = *(const bf16x8*)(vL + (ct * 16 + lr) * 128 + csw);
                acc[ct] = __builtin_amdgcn_mfma_f32_16x16x32_bf16(a, bfr, acc[ct], 0, 0, 0);
            }
        }
        __builtin_amdgcn_s_barrier();
        if (t + 2 < 12) STAGE(t & 1, (t + 2) * 64);
    }
    #undef STAGE

    float sc[4];
    #pragma unroll
    for (int j = 0; j < 4; j++)
        sc[j] = doF ? (1.0f / Z[(size_t)bh * NP + m0 + lg * 4 + j]) : 1.0f;
    __bf16* yb = (doF ? y0f : y0b) + ((size_t)bh * NP + m0) * DW;
    #pragma unroll
    for (int ct = 0; ct < 8; ct++)
        #pragma unroll
        for (int j = 0; j < 4; j++)
            yb[(size_t)(lg * 4 + j) * DW + ct * 16 + lr] = (__bf16)(sc[j] * acc[ct][j]);
}

// ---------------- h-reduce + qgelu -> g (bf16) -------------------------------------
__global__ __launch_bounds__(256) void k_fin1(
    const __bf16* __restrict__ y0f, const __bf16* __restrict__ y0b,
    __bf16* __restrict__ g, int M)
{
    int idx = blockIdx.x * 256 + threadIdx.x;  // one per 8 cols
    int r = idx >> 4;
    int c = (idx & 15) * 8;
    if (r >= M) return;
    int b = r / N_TOK, s = r % N_TOK;
    float sum[8] = {};
    size_t base = ((size_t)b * NH * NP + s) * DW + c;
    #pragma unroll
    for (int h = 0; h < NH; h++) {
        bf16x8 vf_ = *(const bf16x8*)&y0f[base + (size_t)h * NP * DW];
        bf16x8 vb_ = *(const bf16x8*)&y0b[base + (size_t)h * NP * DW];
        #pragma unroll
        for (int i = 0; i < 8; i++) sum[i] += (float)vf_[i] + (float)vb_[i];
    }
    bf16x8 o;
    #pragma unroll
    for (int i = 0; i < 8; i++) {
        float z = sum[i] + 4.5f;
        float gv = z / (1.0f + __expf(-1.702f * z)) - 4.5f;
        o[i] = (__bf16)gv;
    }
    *(bf16x8*)&g[(size_t)r * DW + c] = o;
}

// ---------------- fanin MFMA GEMM + residual ---------------------------------------
__global__ __launch_bounds__(256) void k_fin2(
    const __bf16* __restrict__ g, const float* __restrict__ x,
    const float* __restrict__ fanin_w, const float* __restrict__ fanin_b,
    float* __restrict__ out, int M)
{
    int tid = threadIdx.x;
    int l = tid & 63, wv = tid >> 6;
    int lr = l & 15, lg = l >> 4;
    int m0 = blockIdx.x * 64 + wv * 16;
    f32x4 acc[8] = {};
    int ar = m0 + lr; if (ar >= M) ar = M - 1;
    const __bf16* gp = g + (size_t)ar * DW;
    for (int kk = 0; kk < 128; kk += 32) {
        int ko = kk + lg * 8;
        bf16x8 a = *(const bf16x8*)(gp + ko);
        #pragma unroll
        for (int ct = 0; ct < 8; ct++) {
            const float* wp = fanin_w + (size_t)(ct * 16 + lr) * DW + ko;
            float w0[8];
            *(f32x4*)w0 = *(const f32x4*)wp; *(f32x4*)(w0 + 4) = *(const f32x4*)(wp + 4);
            bf16x8 bfr;
            #pragma unroll
            for (int j2 = 0; j2 < 8; j2++) bfr[j2] = (__bf16)w0[j2];
            acc[ct] = __builtin_amdgcn_mfma_f32_16x16x32_bf16(a, bfr, acc[ct], 0, 0, 0);
        }
    }
    #pragma unroll
    for (int ct = 0; ct < 8; ct++) {
        int c = ct * 16 + lr;
        float fb = fanin_b[c];
        #pragma unroll
        for (int j = 0; j < 4; j++) {
            int r = m0 + lg * 4 + j;
            if (r < M) out[(size_t)r * DW + c] = x[(size_t)r * DW + c] + acc[ct][j] + fb;
        }
    }
}

extern "C" void kernel_launch(void* const* d_in, const int* in_sizes, int n_in,
                              void* d_out, int out_size, void* d_ws, size_t ws_size,
                              hipStream_t stream)
{
    const float* x       = (const float*)d_in[0];
    const float* wk      = (const float*)d_in[1];
    const float* wqv_w   = (const float*)d_in[2];
    const float* wqv_b   = (const float*)d_in[3];
    const float* fanin_w = (const float*)d_in[4];
    const float* fanin_b = (const float*)d_in[5];
    int B = in_sizes[0] / (N_TOK * DW);
    int M = B * N_TOK;
    int Mp = ((M + 127) / 128) * 128;

    char* ws = (char*)d_ws;
    size_t off = 0;
    float*  qbuf = (float*)(ws + off);  off += (size_t)B * NH * NP * DW * 4;  // also y0f
    __bf16* vf_t = (__bf16*)(ws + off); off += (size_t)B * NH * DW * NP * 2;  // also g
    __bf16* vb_t = (__bf16*)(ws + off); off += (size_t)B * NH * DW * NP * 2;
    __bf16* e1   = (__bf16*)(ws + off); off += (size_t)B * NH * NP * NP * 2;
    __bf16* e2   = (__bf16*)(ws + off); off += (size_t)B * NH * NP * NP * 2;
    float*  Z    = (float*)(ws + off);  off += (size_t)B * NH * NP * 4;
    __bf16* y0b  = (__bf16*)(ws + off); off += (size_t)B * NH * NP * DW * 2;
    __bf16* xb   = (__bf16*)(ws + off); off += (size_t)Mp * DW * 2;
    __bf16* wb   = (__bf16*)(ws + off); off += (size_t)3072 * DW * 2;
    if (off > ws_size) return;
    __bf16* y0f = (__bf16*)qbuf;  // qbuf dead after k_scores
    __bf16* g   = vf_t;           // vf_t dead after k_apply

    int zn = B * NH * NP;
    k_zinit<<<(zn + 255) / 256, 256, 0, stream>>>(Z, zn);

    int cvt_threads = (Mp + 3072) * 32;
    k_cvt<<<(cvt_threads + 255) / 256, 256, 0, stream>>>(x, wqv_w, xb, wb, M, Mp);

    dim3 gp(24, Mp / 128);
    k_proj<<<gp, 256, 0, stream>>>(xb, wb, wqv_b, qbuf, vf_t, vb_t, M);

    dim3 gs(NP / 128, NP / 128, B * NH);
    k_scores<<<gs, 256, 0, stream>>>(qbuf, x, wk, e1, e2, Z);

    long total8 = (long)B * NH * DW * NP / 8;
    k_scalevb<<<(int)((total8 + 255) / 256), 256, 0, stream>>>(vb_t, Z, total8);

    dim3 ga(NP / 32, B * NH);
    k_apply<<<ga, 256, 0, stream>>>(e1, e2, vf_t, vb_t, Z, y0f, y0b);

    int f1blocks = (M * (DW / 8) + 255) / 256;
    k_fin1<<<f1blocks, 256, 0, stream>>>(y0f, y0b, g, M);

    k_fin2<<<(M + 63) / 64, 256, 0, stream>>>(g, x, fanin_w, fanin_b, (float*)d_out, M);
}

// Round 11
// 205.113 us; speedup vs baseline: 1.8686x; 1.0302x over previous
//
#include <hip/hip_runtime.h>
#include <hip/hip_bf16.h>
#include <cstdint>

#define N_TOK 744
#define NP    768           // padded token count
#define DW    128           // d_model
#define NH    8

typedef __attribute__((ext_vector_type(4))) float f32x4;
typedef __attribute__((ext_vector_type(4))) unsigned int u32x4;
typedef __attribute__((ext_vector_type(8))) __bf16 bf16x8;
typedef __attribute__((ext_vector_type(4))) __bf16 bf16x4;

__device__ __forceinline__ unsigned int sadu8(unsigned int a, unsigned int b, unsigned int c) {
    unsigned int d;
    asm("v_sad_u8 %0, %1, %2, %3" : "=v"(d) : "v"(a), "v"(b), "v"(c));
    return d;
}

// ---------------- Z init: Z = 1.0 (appended zero-logit contributes exp(0)=1) -------
__global__ void k_zinit(float* Z, int n) {
    int i = blockIdx.x * 256 + threadIdx.x;
    if (i < n) Z[i] = 1.0f;
}

// ---------------- f32 -> bf16 conversion prepass (x -> xb zero-padded, wqv_w -> wb) -
__global__ __launch_bounds__(256) void k_cvt(
    const float* __restrict__ x, const float* __restrict__ wqv_w,
    __bf16* __restrict__ xb, __bf16* __restrict__ wb, int M, int Mp)
{
    int t = blockIdx.x * 256 + threadIdx.x;     // one per 4 elements
    int xgroups = Mp * 32;                       // Mp rows x 32 col-groups
    if (t < xgroups) {
        int r = t >> 5, c4 = (t & 31) * 4;
        f32x4 v = {};
        if (r < M) v = *(const f32x4*)(x + (size_t)r * DW + c4);
        bf16x4 o;
        #pragma unroll
        for (int i = 0; i < 4; i++) o[i] = (__bf16)v[i];
        *(bf16x4*)&xb[(size_t)r * DW + c4] = o;
    } else if (t < xgroups + 3072 * 32) {
        int t2 = t - xgroups;
        int r = t2 >> 5, c4 = (t2 & 31) * 4;
        f32x4 v = *(const f32x4*)(wqv_w + (size_t)r * DW + c4);
        bf16x4 o;
        #pragma unroll
        for (int i = 0; i < 4; i++) o[i] = (__bf16)v[i];
        *(bf16x4*)&wb[(size_t)r * DW + c4] = o;
    }
}

// ---------------- QV projection: 128x128-tile staged MFMA GEMM ---------------------
__global__ __launch_bounds__(256) void k_proj(
    const __bf16* __restrict__ xb, const __bf16* __restrict__ wb,
    const float* __restrict__ wqv_b,
    float* __restrict__ qbuf, __bf16* __restrict__ vf_t, __bf16* __restrict__ vb_t,
    int M)
{
    __shared__ __align__(16) char smem[65536];   // Xt [0,32K) | Wt [32K,64K)
    int bx = blockIdx.x, by = blockIdx.y;
    int tid = threadIdx.x, l = tid & 63, wv = tid >> 6;
    int lr = l & 15, lg = l >> 4;
    bool vpath = (bx >= 8);

    const char* xg = (const char*)xb + (size_t)by * 128 * 256;   // 128 rows x 256B
    const char* wg = (const char*)wb + (size_t)bx * 128 * 256;

    #pragma unroll
    for (int u = wv; u < 64; u += 4) {
        int row = 4 * (u & 31) + (l >> 4);
        unsigned int chunk = (unsigned int)(l & 15) ^ (unsigned int)(row & 7);
        const char* gp = (u < 32 ? xg : wg) + (size_t)row * 256 + chunk * 16;
        char* lp = &smem[u * 1024];
        __builtin_amdgcn_global_load_lds(
            (const __attribute__((address_space(1))) void*)gp,
            (__attribute__((address_space(3))) void*)lp, 16, 0, 0);
    }
    asm volatile("s_waitcnt vmcnt(0)" ::: "memory");
    __builtin_amdgcn_s_barrier();

    const char* Xt = smem;
    const char* Wt = smem + 32768;
    const char* TA = vpath ? Wt : Xt;    // A-operand rows = m-dim
    const char* TB = vpath ? Xt : Wt;    // B-operand rows = n-dim

    f32x4 acc[2][8] = {};
    #pragma unroll
    for (int kk = 0; kk < 4; kk++) {
        int cA = kk * 4 + lg;
        bf16x8 a[2];
        #pragma unroll
        for (int mr = 0; mr < 2; mr++) {
            int row = wv * 32 + mr * 16 + lr;
            a[mr] = *(const bf16x8*)(TA + row * 256 + (cA ^ (row & 7)) * 16);
        }
        #pragma unroll
        for (int nc = 0; nc < 8; nc++) {
            int row = nc * 16 + lr;
            bf16x8 bfr = *(const bf16x8*)(TB + row * 256 + (cA ^ (row & 7)) * 16);
            acc[0][nc] = __builtin_amdgcn_mfma_f32_16x16x32_bf16(a[0], bfr, acc[0][nc], 0, 0, 0);
            acc[1][nc] = __builtin_amdgcn_mfma_f32_16x16x32_bf16(a[1], bfr, acc[1][nc], 0, 0, 0);
        }
    }

    if (!vpath) {
        int hd = bx;
        #pragma unroll
        for (int nc = 0; nc < 8; nc++) {
            int wi = nc * 16 + lr;
            float bias = wqv_b[bx * 128 + wi];
            #pragma unroll
            for (int mr = 0; mr < 2; mr++)
                #pragma unroll
                for (int j = 0; j < 4; j++) {
                    int r = by * 128 + wv * 32 + mr * 16 + lg * 4 + j;
                    if (r >= M) continue;
                    int b = r / N_TOK, s = r % N_TOK;
                    qbuf[(((size_t)b * NH + hd) * NP + s) * DW + wi] = acc[mr][nc][j] + bias;
                }
        }
    } else {
        __bf16* dst0 = (bx < 16) ? vf_t : vb_t;
        int hh = (bx < 16) ? (bx - 8) : (bx - 16);
        #pragma unroll
        for (int mr = 0; mr < 2; mr++)
            #pragma unroll
            for (int j = 0; j < 4; j++) {
                int wi = wv * 32 + mr * 16 + lg * 4 + j;
                float bias = wqv_b[bx * 128 + wi];
                #pragma unroll
                for (int nc = 0; nc < 8; nc++) {
                    int r = by * 128 + nc * 16 + lr;
                    if (r >= M) continue;
                    int b = r / N_TOK, st = r % N_TOK;
                    dst0[(((size_t)b * NH + hh) * DW + wi) * NP + st] =
                        (__bf16)(acc[mr][nc][j] + bias);
                }
            }
    }
}

// ---------------- u8 quantization prepass: qu8 from qbuf, ku8 = u8(x*wk) -----------
// u = trunc(clamp(v,±0.992)*128 + 128.5); bit-identical to prior in-kernel formula.
__global__ __launch_bounds__(256) void k_quant(
    const float* __restrict__ qbuf, const float* __restrict__ x,
    const float* __restrict__ wk,
    unsigned int* __restrict__ qu8, unsigned int* __restrict__ ku8, int B)
{
    int t = blockIdx.x * 256 + threadIdx.x;     // (bh, row, c8): 16 elems each of q,k
    int c8 = t & 7;
    int rr = t >> 3;
    int row = rr % NP;
    int bh = rr / NP;
    if (bh >= B * NH) return;
    int b = bh >> 3, h = bh & 7;
    bool valid = row < N_TOK;
    int w0 = c8 * 16;
    const float* qp = qbuf + ((size_t)bh * NP + row) * DW + w0;
    const float* xp = x + ((size_t)b * N_TOK + (valid ? row : 0)) * DW + w0;
    const float* wp = wk + h * DW + w0;
    const float CL = 0.9921875f;
    unsigned int outq[4], outk[4];
    #pragma unroll
    for (int u = 0; u < 4; u++) {
        f32x4 qv = {}, xv = {};
        if (valid) { qv = *(const f32x4*)(qp + u * 4); xv = *(const f32x4*)(xp + u * 4); }
        f32x4 wv = *(const f32x4*)(wp + u * 4);
        unsigned int pq = 0, pk = 0;
        #pragma unroll
        for (int e = 0; e < 4; e++) {
            float a = fminf(fmaxf(qv[e], -CL), CL);
            pq |= ((unsigned int)__builtin_fmaf(a, 128.0f, 128.5f)) << (8 * e);
            float c = fminf(fmaxf(xv[e] * wv[e], -CL), CL);
            pk |= ((unsigned int)__builtin_fmaf(c, 128.0f, 128.5f)) << (8 * e);
        }
        outq[u] = pq; outk[u] = pk;
    }
    size_t dst = ((size_t)bh * NP + row) * 32 + c8 * 4;
    *(u32x4*)&qu8[dst] = *(u32x4*)outq;
    *(u32x4*)&ku8[dst] = *(u32x4*)outk;
}

// ---------------- L1 scores via packed v_sad_u8 on prequantized inputs -------------
// kt split into two halves offset by +16B (mod 128B) so kv ds_read_b128 is 2-way
// (= free) instead of 4-way banked.
__global__ __launch_bounds__(256) void k_scores(
    const unsigned int* __restrict__ qu8, const unsigned int* __restrict__ ku8,
    __bf16* __restrict__ e1, __bf16* __restrict__ e2, float* __restrict__ Z)
{
    __shared__ __align__(16) unsigned int qt[32][132];        // [w-group][s-row]
    __shared__ __align__(16) unsigned int kts[2 * 2176 + 4];  // kt0 | pad16B | kt1, rows 68
    int bh = blockIdx.z;
    int s0 = blockIdx.y * 128, d0 = blockIdx.x * 128;
    int tid = threadIdx.x;
    int ty = tid >> 4, tx = tid & 15;      // 16x16 threads, each 8x8 outputs

    // staging: thread-per-row (waves uniform: w0,w1=q rows; w2=k rows 0-63; w3=k 64-127)
    {
        int row = tid & 127;
        bool isq = tid < 128;
        const unsigned int* src = isq
            ? qu8 + ((size_t)bh * NP + s0 + row) * 32
            : ku8 + ((size_t)bh * NP + d0 + row) * 32;
        unsigned int buf[32];
        #pragma unroll
        for (int c = 0; c < 8; c++)
            *(u32x4*)&buf[c * 4] = *(const u32x4*)(src + c * 4);
        if (isq) {
            #pragma unroll
            for (int i = 0; i < 32; i++) qt[i][row] = buf[i];
        } else {
            unsigned int* dst = (row < 64) ? &kts[row] : &kts[2180 + (row - 64)];
            #pragma unroll
            for (int i = 0; i < 32; i++) dst[i * 68] = buf[i];
        }
    }
    __syncthreads();

    const char* kbase = (const char*)((tx < 8) ? &kts[tx * 8] : &kts[2180 + (tx - 8) * 8]);
    unsigned int acc[8][8] = {};
    #pragma unroll 4
    for (int g = 0; g < 32; g++) {
        unsigned int qv[8], kv[8];
        *(u32x4*)&qv[0] = *(const u32x4*)&qt[g][ty * 8];
        *(u32x4*)&qv[4] = *(const u32x4*)&qt[g][ty * 8 + 4];
        *(u32x4*)&kv[0] = *(const u32x4*)(kbase + g * 272);
        *(u32x4*)&kv[4] = *(const u32x4*)(kbase + g * 272 + 16);
        #pragma unroll
        for (int i = 0; i < 8; i++)
            #pragma unroll
            for (int j = 0; j < 8; j++)
                acc[i][j] = sadu8(qv[i], kv[j], acc[i][j]);
    }

    const float SS = 0.08838834764831845f / 128.0f;
    float e[8][8]; float colsum[8] = {};
    int sb = s0 + ty * 8, db = d0 + tx * 8;
    #pragma unroll
    for (int i = 0; i < 8; i++)
        #pragma unroll
        for (int j = 0; j < 8; j++) {
            float ev = ((sb + i) < N_TOK && (db + j) < N_TOK)
                       ? __expf(-(float)acc[i][j] * SS) : 0.0f;
            e[i][j] = ev; colsum[j] += ev;
        }
    size_t ebase = (size_t)bh * NP * NP;
    #pragma unroll
    for (int i = 0; i < 8; i++) {
        bf16x8 v;
        #pragma unroll
        for (int j = 0; j < 8; j++) v[j] = (__bf16)e[i][j];
        *(bf16x8*)&e2[ebase + (size_t)(sb + i) * NP + db] = v;
    }
    #pragma unroll
    for (int j = 0; j < 8; j++) {
        bf16x8 v;
        #pragma unroll
        for (int i = 0; i < 8; i++) v[i] = (__bf16)e[i][j];
        *(bf16x8*)&e1[ebase + (size_t)(db + j) * NP + sb] = v;
    }
    __syncthreads();                       // qt reused as reduce scratch
    float* red = (float*)&qt[0][0];
    #pragma unroll
    for (int j = 0; j < 8; j++) red[ty * 128 + tx * 8 + j] = colsum[j];
    __syncthreads();
    if (tid < 128) {
        float z = 0;
        #pragma unroll
        for (int r = 0; r < 16; r++) z += red[r * 128 + tid];
        atomicAdd(&Z[(size_t)bh * NP + d0 + tid], z);
    }
}

// ---------------- fold 1/Z[token] into Vb (in place) ------------------------------
__global__ void k_scalevb(__bf16* vb_t, const float* __restrict__ Z, long total8)
{
    long idx = (long)blockIdx.x * blockDim.x + threadIdx.x;
    if (idx >= total8) return;
    size_t base = (size_t)idx * 8;
    int s = (int)(base % NP);
    int bh = (int)((base / NP) / DW);
    bf16x8 v = *(bf16x8*)&vb_t[base];
    const float* Zp = Z + (size_t)bh * NP + s;
    bf16x8 o;
    #pragma unroll
    for (int i = 0; i < 8; i++) o[i] = (__bf16)((float)v[i] / Zp[i]);
    *(bf16x8*)&vb_t[base] = o;
}

// ---------------- attention apply: LDS double-buffered pipelined GEMMs -------------
__global__ __launch_bounds__(256) void k_apply(
    const __bf16* __restrict__ e1, const __bf16* __restrict__ e2,
    const __bf16* __restrict__ vf_t, const __bf16* __restrict__ vb_t,
    const float* __restrict__ Z, __bf16* __restrict__ y0f, __bf16* __restrict__ y0b)
{
    __shared__ __align__(16) char smem[2][40960];   // 80 KB: 2 blocks/CU
    int bh = blockIdx.y;
    int tid = threadIdx.x;
    int l = tid & 63, wv = tid >> 6;
    int lr = l & 15, lg = l >> 4;
    int m0b = blockIdx.x * 32;
    int m0 = m0b + (wv & 1) * 16;
    bool doF = (wv < 2);

    const char* e1b = (const char*)e1 + 2 * ((size_t)bh * NP * NP + (size_t)m0b * NP);
    const char* e2b = (const char*)e2 + 2 * ((size_t)bh * NP * NP + (size_t)m0b * NP);
    const char* vfb = (const char*)vf_t + 2 * ((size_t)bh * DW * NP);
    const char* vbb = (const char*)vb_t + 2 * ((size_t)bh * DW * NP);
    unsigned int swz = (16u * (l & 7)) ^ (((unsigned)(l >> 3)) << 4);  // pre-swizzled source
    size_t rowoff = (size_t)(l >> 3) * (NP * 2);                       // row within 8-row unit

    #define STAGE(bi, kk) do {                                                        \
        for (int u = wv; u < 40; u += 4) {                                            \
            char* lp = &smem[bi][u * 1024];                                           \
            const char* gp;                                                           \
            if (u < 4)       gp = e1b + (size_t)(8 * u) * (NP * 2);                   \
            else if (u < 8)  gp = e2b + (size_t)(8 * (u - 4)) * (NP * 2);             \
            else if (u < 24) gp = vfb + (size_t)(8 * (u - 8)) * (NP * 2);             \
            else             gp = vbb + (size_t)(8 * (u - 24)) * (NP * 2);            \
            gp += rowoff + (size_t)(kk) * 2 + swz;                                    \
            __builtin_amdgcn_global_load_lds(                                         \
                (const __attribute__((address_space(1))) void*)gp,                    \
                (__attribute__((address_space(3))) void*)lp, 16, 0, 0);               \
        }                                                                             \
    } while (0)

    const char* eL0 = &smem[0][doF ? 0 : 4096];
    const char* vL0 = &smem[0][doF ? 8192 : 24576];
    int mloc = (wv & 1) * 16 + lr;
    unsigned int rswz = ((unsigned)(lr & 7)) << 4;

    f32x4 acc[8] = {};
    STAGE(0, 0);
    STAGE(1, 64);
    for (int t = 0; t < 12; t++) {
        if (t < 11) asm volatile("s_waitcnt vmcnt(10)" ::: "memory");
        else        asm volatile("s_waitcnt vmcnt(0)" ::: "memory");
        __builtin_amdgcn_s_barrier();
        const char* eL = eL0 + (t & 1) * 40960;
        const char* vL = vL0 + (t & 1) * 40960;
        #pragma unroll
        for (int ph = 0; ph < 2; ph++) {
            unsigned int csw = (ph * 64 + lg * 16) ^ rswz;
            bf16x8 a = *(const bf16x8*)(eL + mloc * 128 + csw);
            #pragma unroll
            for (int ct = 0; ct < 8; ct++) {
                bf16x8 bfr = *(const bf16x8*)(vL + (ct * 16 + lr) * 128 + csw);
                acc[ct] = __builtin_amdgcn_mfma_f32_16x16x32_bf16(a, bfr, acc[ct], 0, 0, 0);
            }
        }
        __builtin_amdgcn_s_barrier();
        if (t + 2 < 12) STAGE(t & 1, (t + 2) * 64);
    }
    #undef STAGE

    float sc[4];
    #pragma unroll
    for (int j = 0; j < 4; j++)
        sc[j] = doF ? (1.0f / Z[(size_t)bh * NP + m0 + lg * 4 + j]) : 1.0f;
    __bf16* yb = (doF ? y0f : y0b) + ((size_t)bh * NP + m0) * DW;
    #pragma unroll
    for (int ct = 0; ct < 8; ct++)
        #pragma unroll
        for (int j = 0; j < 4; j++)
            yb[(size_t)(lg * 4 + j) * DW + ct * 16 + lr] = (__bf16)(sc[j] * acc[ct][j]);
}

// ---------------- h-reduce + qgelu -> g (bf16) -------------------------------------
__global__ __launch_bounds__(256) void k_fin1(
    const __bf16* __restrict__ y0f, const __bf16* __restrict__ y0b,
    __bf16* __restrict__ g, int M)
{
    int idx = blockIdx.x * 256 + threadIdx.x;  // one per 8 cols
    int r = idx >> 4;
    int c = (idx & 15) * 8;
    if (r >= M) return;
    int b = r / N_TOK, s = r % N_TOK;
    float sum[8] = {};
    size_t base = ((size_t)b * NH * NP + s) * DW + c;
    #pragma unroll
    for (int h = 0; h < NH; h++) {
        bf16x8 vf_ = *(const bf16x8*)&y0f[base + (size_t)h * NP * DW];
        bf16x8 vb_ = *(const bf16x8*)&y0b[base + (size_t)h * NP * DW];
        #pragma unroll
        for (int i = 0; i < 8; i++) sum[i] += (float)vf_[i] + (float)vb_[i];
    }
    bf16x8 o;
    #pragma unroll
    for (int i = 0; i < 8; i++) {
        float z = sum[i] + 4.5f;
        float gv = z / (1.0f + __expf(-1.702f * z)) - 4.5f;
        o[i] = (__bf16)gv;
    }
    *(bf16x8*)&g[(size_t)r * DW + c] = o;
}

// ---------------- fanin MFMA GEMM + residual ---------------------------------------
__global__ __launch_bounds__(256) void k_fin2(
    const __bf16* __restrict__ g, const float* __restrict__ x,
    const float* __restrict__ fanin_w, const float* __restrict__ fanin_b,
    float* __restrict__ out, int M)
{
    int tid = threadIdx.x;
    int l = tid & 63, wv = tid >> 6;
    int lr = l & 15, lg = l >> 4;
    int m0 = blockIdx.x * 64 + wv * 16;
    f32x4 acc[8] = {};
    int ar = m0 + lr; if (ar >= M) ar = M - 1;
    const __bf16* gp = g + (size_t)ar * DW;
    for (int kk = 0; kk < 128; kk += 32) {
        int ko = kk + lg * 8;
        bf16x8 a = *(const bf16x8*)(gp + ko);
        #pragma unroll
        for (int ct = 0; ct < 8; ct++) {
            const float* wp = fanin_w + (size_t)(ct * 16 + lr) * DW + ko;
            float w0[8];
            *(f32x4*)w0 = *(const f32x4*)wp; *(f32x4*)(w0 + 4) = *(const f32x4*)(wp + 4);
            bf16x8 bfr;
            #pragma unroll
            for (int j2 = 0; j2 < 8; j2++) bfr[j2] = (__bf16)w0[j2];
            acc[ct] = __builtin_amdgcn_mfma_f32_16x16x32_bf16(a, bfr, acc[ct], 0, 0, 0);
        }
    }
    #pragma unroll
    for (int ct = 0; ct < 8; ct++) {
        int c = ct * 16 + lr;
        float fb = fanin_b[c];
        #pragma unroll
        for (int j = 0; j < 4; j++) {
            int r = m0 + lg * 4 + j;
            if (r < M) out[(size_t)r * DW + c] = x[(size_t)r * DW + c] + acc[ct][j] + fb;
        }
    }
}

extern "C" void kernel_launch(void* const* d_in, const int* in_sizes, int n_in,
                              void* d_out, int out_size, void* d_ws, size_t ws_size,
                              hipStream_t stream)
{
    const float* x       = (const float*)d_in[0];
    const float* wk      = (const float*)d_in[1];
    const float* wqv_w   = (const float*)d_in[2];
    const float* wqv_b   = (const float*)d_in[3];
    const float* fanin_w = (const float*)d_in[4];
    const float* fanin_b = (const float*)d_in[5];
    int B = in_sizes[0] / (N_TOK * DW);
    int M = B * N_TOK;
    int Mp = ((M + 127) / 128) * 128;

    char* ws = (char*)d_ws;
    size_t off = 0;
    float*  qbuf = (float*)(ws + off);  off += (size_t)B * NH * NP * DW * 4;  // also y0f
    __bf16* vf_t = (__bf16*)(ws + off); off += (size_t)B * NH * DW * NP * 2;  // also g
    __bf16* vb_t = (__bf16*)(ws + off); off += (size_t)B * NH * DW * NP * 2;
    __bf16* e1   = (__bf16*)(ws + off); off += (size_t)B * NH * NP * NP * 2;
    __bf16* e2   = (__bf16*)(ws + off); off += (size_t)B * NH * NP * NP * 2;
    float*  Z    = (float*)(ws + off);  off += (size_t)B * NH * NP * 4;
    __bf16* y0b  = (__bf16*)(ws + off); off += (size_t)B * NH * NP * DW * 2;
    __bf16* xb   = (__bf16*)(ws + off); off += (size_t)Mp * DW * 2;
    __bf16* wb   = (__bf16*)(ws + off); off += (size_t)3072 * DW * 2;
    unsigned int* qu8 = (unsigned int*)(ws + off); off += (size_t)B * NH * NP * 32 * 4;
    unsigned int* ku8 = (unsigned int*)(ws + off); off += (size_t)B * NH * NP * 32 * 4;
    if (off > ws_size) return;
    __bf16* y0f = (__bf16*)qbuf;  // qbuf dead after k_quant
    __bf16* g   = vf_t;           // vf_t dead after k_apply

    int zn = B * NH * NP;
    k_zinit<<<(zn + 255) / 256, 256, 0, stream>>>(Z, zn);

    int cvt_threads = (Mp + 3072) * 32;
    k_cvt<<<(cvt_threads + 255) / 256, 256, 0, stream>>>(x, wqv_w, xb, wb, M, Mp);

    dim3 gp(24, Mp / 128);
    k_proj<<<gp, 256, 0, stream>>>(xb, wb, wqv_b, qbuf, vf_t, vb_t, M);

    int qthreads = B * NH * NP * 8;
    k_quant<<<(qthreads + 255) / 256, 256, 0, stream>>>(qbuf, x, wk, qu8, ku8, B);

    dim3 gs(NP / 128, NP / 128, B * NH);
    k_scores<<<gs, 256, 0, stream>>>(qu8, ku8, e1, e2, Z);

    long total8 = (long)B * NH * DW * NP / 8;
    k_scalevb<<<(int)((total8 + 255) / 256), 256, 0, stream>>>(vb_t, Z, total8);

    dim3 ga(NP / 32, B * NH);
    k_apply<<<ga, 256, 0, stream>>>(e1, e2, vf_t, vb_t, Z, y0f, y0b);

    int f1blocks = (M * (DW / 8) + 255) / 256;
    k_fin1<<<f1blocks, 256, 0, stream>>>(y0f, y0b, g, M);

    k_fin2<<<(M + 63) / 64, 256, 0, stream>>>(g, x, fanin_w, fanin_b, (float*)d_out, M);
}